// Round 1
// baseline (499.257 us; speedup 1.0000x reference)
//
#include <hip/hip_runtime.h>
#include <hip/hip_bf16.h>

typedef __hip_bfloat16 bf16_t;
typedef __attribute__((ext_vector_type(8))) short bf16x8;
typedef __attribute__((ext_vector_type(4))) float f32x4;

#define S_LEN   2048
#define D_MODEL 2048
#define N_QH    32
#define N_KVH   8
#define HEAD_D  64
#define KV_D    512
#define M_ROWS  4096
#define ATT_SCALE 0.125f
#define LOG2E_F 1.44269504088896340736f

// ---------------- RoPE table (double precision, [2048][32] cos/sin) ----------------
__global__ void rope_table_kernel(float* __restrict__ cosT, float* __restrict__ sinT) {
    int pos = blockIdx.x * 2 + (threadIdx.x >> 5);
    int j   = threadIdx.x & 31;
    double invf = pow(10000.0, -(double)(2 * j) / 64.0);
    double a = (double)pos * invf;
    cosT[pos * 32 + j] = (float)cos(a);
    sinT[pos * 32 + j] = (float)sin(a);
}

// ---------------- weight transpose + convert: W[K][N] f32 -> Wt[N][K] bf16 ----------------
__global__ void wt_conv_kernel(const float* __restrict__ W, bf16_t* __restrict__ Wt,
                               int K, int N) {
    __shared__ float tile[32][33];
    int n0 = blockIdx.x * 32, k0 = blockIdx.y * 32;
    int tx = threadIdx.x & 31, ty = threadIdx.x >> 5;   // 32 x 8
#pragma unroll
    for (int i = 0; i < 4; i++) {
        int r = ty + i * 8;
        tile[r][tx] = W[(size_t)(k0 + r) * N + n0 + tx];
    }
    __syncthreads();
#pragma unroll
    for (int i = 0; i < 4; i++) {
        int r = ty + i * 8;
        Wt[(size_t)(n0 + r) * K + k0 + tx] = __float2bfloat16(tile[tx][r]);
    }
}

// ---------------- f32 -> bf16 elementwise (x4 vectorized) ----------------
struct __align__(8) bf16x4s { bf16_t x, y, z, w; };
__global__ void conv_bf16_kernel(const float* __restrict__ X, bf16_t* __restrict__ Y) {
    int i = blockIdx.x * 256 + threadIdx.x;
    float4 v = ((const float4*)X)[i];
    bf16x4s o;
    o.x = __float2bfloat16(v.x);
    o.y = __float2bfloat16(v.y);
    o.z = __float2bfloat16(v.z);
    o.w = __float2bfloat16(v.w);
    ((bf16x4s*)Y)[i] = o;
}

// ---------------- async 16B global->LDS ----------------
__device__ __forceinline__ void async_copy16(const bf16_t* g, bf16_t* l) {
    __builtin_amdgcn_global_load_lds((const __attribute__((address_space(1))) void*)g,
                                     (__attribute__((address_space(3))) void*)l, 16, 0, 0);
}

// ---------------- GEMM: C[M][N] = A[M][K] (bf16) * Bt[N][K]^T (bf16) + bias ----------------
// ROPE=1: apply rotary embedding per 64-wide head in the epilogue, write bf16.
// OUTF32=1: write fp32 (final output projection). Else write bf16.
template <int ROPE, int OUTF32>
__global__ __launch_bounds__(256, 2)
void gqa_gemm_kernel(const bf16_t* __restrict__ A, const bf16_t* __restrict__ Bt,
                     const float* __restrict__ bias, void* __restrict__ Cout,
                     int M, int N, int K,
                     const float* __restrict__ cosT, const float* __restrict__ sinT) {
    __shared__ __align__(16) bf16_t As[128 * 32];
    __shared__ __align__(16) bf16_t Bs[128 * 32];

    const int t = threadIdx.x;
    const int am0 = blockIdx.y * 128;
    const int bn0 = blockIdx.x * 128;

    const int l = t & 63, w = t >> 6;
    const int wr = w >> 1, wc = w & 1;       // 2x2 wave grid, 64x64 per wave
    const int lr = l & 15, lk = l >> 4;

    f32x4 acc[4][4];
#pragma unroll
    for (int i = 0; i < 4; i++)
#pragma unroll
        for (int j = 0; j < 4; j++) acc[i][j] = (f32x4)0.0f;

    const int srow = t >> 2;            // 0..63
    const int scol = (t & 3) * 8;       // element col within 32-wide K tile
    const bf16_t* aptr = A + (size_t)(am0 + srow) * K + scol;
    const bf16_t* bptr = Bt + (size_t)(bn0 + srow) * K + scol;
    bf16_t* aLds = As + t * 8;          // t*16 bytes
    bf16_t* bLds = Bs + t * 8;

    for (int k0 = 0; k0 < K; k0 += 32) {
        async_copy16(aptr + k0,              aLds);
        async_copy16(aptr + (size_t)64 * K + k0, aLds + 2048);
        async_copy16(bptr + k0,              bLds);
        async_copy16(bptr + (size_t)64 * K + k0, bLds + 2048);
        __syncthreads();

        bf16x8 af[4], bfr[4];
#pragma unroll
        for (int mi = 0; mi < 4; mi++)
            af[mi] = *(const bf16x8*)&As[(wr * 64 + mi * 16 + lr) * 32 + lk * 8];
#pragma unroll
        for (int ni = 0; ni < 4; ni++)
            bfr[ni] = *(const bf16x8*)&Bs[(wc * 64 + ni * 16 + lr) * 32 + lk * 8];
#pragma unroll
        for (int mi = 0; mi < 4; mi++)
#pragma unroll
            for (int ni = 0; ni < 4; ni++)
                acc[mi][ni] = __builtin_amdgcn_mfma_f32_16x16x32_bf16(af[mi], bfr[ni],
                                                                      acc[mi][ni], 0, 0, 0);
        __syncthreads();
    }

    // Epilogue. C/D layout: col = lane&15, row = (lane>>4)*4 + reg  [verified m89/m91]
#pragma unroll
    for (int mi = 0; mi < 4; mi++) {
#pragma unroll
        for (int reg = 0; reg < 4; reg++) {
            int row = am0 + wr * 64 + mi * 16 + lk * 4 + reg;
            if (OUTF32) {
                float* out = (float*)Cout;
#pragma unroll
                for (int ni = 0; ni < 4; ni++) {
                    int col = bn0 + wc * 64 + ni * 16 + lr;
                    out[(size_t)row * N + col] = acc[mi][ni][reg] + bias[col];
                }
            } else if (ROPE) {
                bf16_t* out = (bf16_t*)Cout;
                int pos = row & (S_LEN - 1);
#pragma unroll
                for (int np = 0; np < 2; np++) {
                    int j = np * 16 + lr;              // d % 32 (head-local)
                    float cs = cosT[pos * 32 + j];
                    float sn = sinT[pos * 32 + j];
                    int col1 = bn0 + wc * 64 + np * 16 + lr;   // d < 32 half
                    float x1 = acc[mi][np][reg] + bias[col1];
                    float x2 = acc[mi][np + 2][reg] + bias[col1 + 32];
                    out[(size_t)row * N + col1]      = __float2bfloat16(x1 * cs - x2 * sn);
                    out[(size_t)row * N + col1 + 32] = __float2bfloat16(x2 * cs + x1 * sn);
                }
            } else {
                bf16_t* out = (bf16_t*)Cout;
#pragma unroll
                for (int ni = 0; ni < 4; ni++) {
                    int col = bn0 + wc * 64 + ni * 16 + lr;
                    out[(size_t)row * N + col] =
                        __float2bfloat16(acc[mi][ni][reg] + bias[col]);
                }
            }
        }
    }
}

// ---------------- causal GQA flash attention ----------------
// grid (S/64, QH, B); block 256 = 4 waves, each wave owns 16 q-rows.
__global__ __launch_bounds__(256, 2)
void gqa_attn_kernel(const bf16_t* __restrict__ Q, const bf16_t* __restrict__ Kb,
                     const bf16_t* __restrict__ Vb, bf16_t* __restrict__ Ctx) {
    __shared__ __align__(16) bf16_t Ks[64 * 72];        // [key][d], padded rows
    __shared__ __align__(16) bf16_t Vt[64 * 72];        // [d][key], padded rows
    __shared__ __align__(16) bf16_t Pw[4][16 * 72];     // per-wave P, padded rows

    const int t = threadIdx.x, l = t & 63, w = t >> 6;
    const int lr = l & 15, lk = l >> 4;
    const int qt = blockIdx.x;
    const int h  = blockIdx.y;
    const int b  = blockIdx.z;
    const int kvh = h >> 2;                  // G = 4
    const int q0w = qt * 64 + w * 16;

    // Q fragments (A operand): row = lane&15 -> q, k = (lane>>4)*8+i -> d
    bf16x8 qf[2];
    {
        const bf16_t* qrow = Q + ((size_t)(b * S_LEN + q0w + lr)) * D_MODEL + h * HEAD_D;
        qf[0] = *(const bf16x8*)(qrow + lk * 8);
        qf[1] = *(const bf16x8*)(qrow + 32 + lk * 8);
    }

    float mrow[4], lrow[4];
    f32x4 oacc[4];                           // [d-frag]; lanes hold 4 q-rows each
#pragma unroll
    for (int r = 0; r < 4; r++) { mrow[r] = -1e30f; lrow[r] = 0.f; }
#pragma unroll
    for (int df = 0; df < 4; df++) oacc[df] = (f32x4)0.0f;

    const int nkt = qt + 1;
    for (int kt = 0; kt < nkt; kt++) {
        // ---- stage K (row-major, padded) and V (transposed, padded) ----
        {
            int key = t >> 2;
            int d0  = (t & 3) * 16;
            const bf16_t* krow = Kb + ((size_t)(b * S_LEN + kt * 64 + key)) * KV_D + kvh * HEAD_D + d0;
            const bf16_t* vrow = Vb + ((size_t)(b * S_LEN + kt * 64 + key)) * KV_D + kvh * HEAD_D + d0;
            bf16x8 k0v = *(const bf16x8*)krow;
            bf16x8 k1v = *(const bf16x8*)(krow + 8);
            *(bf16x8*)&Ks[key * 72 + d0]     = k0v;
            *(bf16x8*)&Ks[key * 72 + d0 + 8] = k1v;
            bf16x8 v0v = *(const bf16x8*)vrow;
            bf16x8 v1v = *(const bf16x8*)(vrow + 8);
#pragma unroll
            for (int j = 0; j < 8; j++) Vt[(d0 + j) * 72 + key]     = ((const bf16_t*)&v0v)[j];
#pragma unroll
            for (int j = 0; j < 8; j++) Vt[(d0 + 8 + j) * 72 + key] = ((const bf16_t*)&v1v)[j];
        }
        __syncthreads();

        // ---- scores: S[16q][64k] via 8 MFMA ----
        f32x4 sfr[4];
#pragma unroll
        for (int ni = 0; ni < 4; ni++) sfr[ni] = (f32x4)0.0f;
#pragma unroll
        for (int ni = 0; ni < 4; ni++)
#pragma unroll
            for (int ks = 0; ks < 2; ks++) {
                bf16x8 kf = *(const bf16x8*)&Ks[(ni * 16 + lr) * 72 + ks * 32 + lk * 8];
                sfr[ni] = __builtin_amdgcn_mfma_f32_16x16x32_bf16(qf[ks], kf, sfr[ni], 0, 0, 0);
            }

        // ---- scale + causal mask (base-2 domain) ----
        float p[4][4];
        float mt[4];
#pragma unroll
        for (int r = 0; r < 4; r++) mt[r] = -1e30f;
        const bool diag = (kt == qt);
#pragma unroll
        for (int ni = 0; ni < 4; ni++)
#pragma unroll
            for (int r = 0; r < 4; r++) {
                float sc = sfr[ni][r] * (ATT_SCALE * LOG2E_F);
                if (diag) {
                    int keyg = kt * 64 + ni * 16 + lr;
                    int qg   = q0w + lk * 4 + r;
                    if (keyg > qg) sc = -1e30f;
                }
                p[ni][r] = sc;
                mt[r] = fmaxf(mt[r], sc);
            }
        // row-max across the 16 lanes of each quarter-wave
#pragma unroll
        for (int r = 0; r < 4; r++)
            for (int msk = 1; msk < 16; msk <<= 1)
                mt[r] = fmaxf(mt[r], __shfl_xor(mt[r], msk));

        float csc[4], rs[4];
#pragma unroll
        for (int r = 0; r < 4; r++) {
            float mn = fmaxf(mrow[r], mt[r]);
            csc[r] = exp2f(mrow[r] - mn);
            mrow[r] = mn;
            rs[r] = 0.f;
        }
#pragma unroll
        for (int ni = 0; ni < 4; ni++)
#pragma unroll
            for (int r = 0; r < 4; r++) {
                float pv = exp2f(p[ni][r] - mrow[r]);
                p[ni][r] = pv;
                rs[r] += pv;
            }
#pragma unroll
        for (int r = 0; r < 4; r++) {
            for (int msk = 1; msk < 16; msk <<= 1) rs[r] += __shfl_xor(rs[r], msk);
            lrow[r] = lrow[r] * csc[r] + rs[r];
#pragma unroll
            for (int df = 0; df < 4; df++) oacc[df][r] *= csc[r];
        }

        // ---- P -> LDS (bf16), reread in A-fragment layout ----
#pragma unroll
        for (int ni = 0; ni < 4; ni++)
#pragma unroll
            for (int r = 0; r < 4; r++)
                Pw[w][(lk * 4 + r) * 72 + ni * 16 + lr] = __float2bfloat16(p[ni][r]);

#pragma unroll
        for (int ks = 0; ks < 2; ks++) {
            bf16x8 pf = *(const bf16x8*)&Pw[w][lr * 72 + ks * 32 + lk * 8];
#pragma unroll
            for (int df = 0; df < 4; df++) {
                bf16x8 vf = *(const bf16x8*)&Vt[(df * 16 + lr) * 72 + ks * 32 + lk * 8];
                oacc[df] = __builtin_amdgcn_mfma_f32_16x16x32_bf16(pf, vf, oacc[df], 0, 0, 0);
            }
        }
        __syncthreads();
    }

    // ---- normalize + write ctx (bf16, [B,S,DIM] layout) ----
#pragma unroll
    for (int r = 0; r < 4; r++) {
        float inv = 1.0f / lrow[r];
        int qg = q0w + lk * 4 + r;
        bf16_t* crow = Ctx + ((size_t)(b * S_LEN + qg)) * D_MODEL + h * HEAD_D;
#pragma unroll
        for (int df = 0; df < 4; df++)
            crow[df * 16 + lr] = __float2bfloat16(oacc[df][r] * inv);
    }
}

extern "C" void kernel_launch(void* const* d_in, const int* in_sizes, int n_in,
                              void* d_out, int out_size, void* d_ws, size_t ws_size,
                              hipStream_t stream) {
    const float* query = (const float*)d_in[0];
    const float* key_  = (const float*)d_in[1];
    const float* value = (const float*)d_in[2];
    const float* w_q = (const float*)d_in[3];
    const float* b_q = (const float*)d_in[4];
    const float* w_k = (const float*)d_in[5];
    const float* b_k = (const float*)d_in[6];
    const float* w_v = (const float*)d_in[7];
    const float* b_v = (const float*)d_in[8];
    const float* w_o = (const float*)d_in[9];
    const float* b_o = (const float*)d_in[10];
    float* out = (float*)d_out;

    char* ws = (char*)d_ws;
    bf16_t* Abuf = (bf16_t*)(ws);                       // 16MB  (A staging, reused as ctx)
    bf16_t* qb   = (bf16_t*)(ws + (size_t)(16 << 20));  // 16MB
    bf16_t* kb   = (bf16_t*)(ws + (size_t)(32 << 20));  // 4MB
    bf16_t* vb   = (bf16_t*)(ws + (size_t)(36 << 20));  // 4MB
    bf16_t* wtq  = (bf16_t*)(ws + (size_t)(40 << 20));  // 8MB
    bf16_t* wtk  = (bf16_t*)(ws + (size_t)(48 << 20));  // 2MB
    bf16_t* wtv  = (bf16_t*)(ws + (size_t)(50 << 20));  // 2MB
    bf16_t* wto  = (bf16_t*)(ws + (size_t)(52 << 20));  // 8MB
    float* cosT  = (float*)(ws + (size_t)(60 << 20));   // 256KB
    float* sinT  = (float*)(ws + (size_t)(60 << 20) + (256 << 10));

    rope_table_kernel<<<S_LEN / 2, 64, 0, stream>>>(cosT, sinT);

    wt_conv_kernel<<<dim3(D_MODEL / 32, D_MODEL / 32), 256, 0, stream>>>(w_q, wtq, D_MODEL, D_MODEL);
    wt_conv_kernel<<<dim3(KV_D / 32, D_MODEL / 32), 256, 0, stream>>>(w_k, wtk, D_MODEL, KV_D);
    wt_conv_kernel<<<dim3(KV_D / 32, D_MODEL / 32), 256, 0, stream>>>(w_v, wtv, D_MODEL, KV_D);
    wt_conv_kernel<<<dim3(D_MODEL / 32, D_MODEL / 32), 256, 0, stream>>>(w_o, wto, D_MODEL, D_MODEL);

    const int n4blocks = (M_ROWS * D_MODEL / 4) / 256;  // 8192

    // Q projection (+RoPE)
    conv_bf16_kernel<<<n4blocks, 256, 0, stream>>>(query, Abuf);
    gqa_gemm_kernel<1, 0><<<dim3(D_MODEL / 128, M_ROWS / 128), 256, 0, stream>>>(
        Abuf, wtq, b_q, qb, M_ROWS, D_MODEL, D_MODEL, cosT, sinT);
    // K projection (+RoPE)
    conv_bf16_kernel<<<n4blocks, 256, 0, stream>>>(key_, Abuf);
    gqa_gemm_kernel<1, 0><<<dim3(KV_D / 128, M_ROWS / 128), 256, 0, stream>>>(
        Abuf, wtk, b_k, kb, M_ROWS, KV_D, D_MODEL, cosT, sinT);
    // V projection
    conv_bf16_kernel<<<n4blocks, 256, 0, stream>>>(value, Abuf);
    gqa_gemm_kernel<0, 0><<<dim3(KV_D / 128, M_ROWS / 128), 256, 0, stream>>>(
        Abuf, wtv, b_v, vb, M_ROWS, KV_D, D_MODEL, cosT, sinT);

    // Attention -> ctx (reuses Abuf)
    gqa_attn_kernel<<<dim3(S_LEN / 64, N_QH, 2), 256, 0, stream>>>(qb, kb, vb, Abuf);

    // Output projection -> fp32 d_out
    gqa_gemm_kernel<0, 1><<<dim3(D_MODEL / 128, M_ROWS / 128), 256, 0, stream>>>(
        Abuf, wto, b_o, out, M_ROWS, D_MODEL, D_MODEL, cosT, sinT);
}

// Round 2
// 479.381 us; speedup vs baseline: 1.0415x; 1.0415x over previous
//
#include <hip/hip_runtime.h>
#include <hip/hip_bf16.h>

typedef __hip_bfloat16 bf16_t;
typedef __attribute__((ext_vector_type(8))) short bf16x8;
typedef __attribute__((ext_vector_type(4))) float f32x4;

#define S_LEN   2048
#define D_MODEL 2048
#define N_QH    32
#define N_KVH   8
#define HEAD_D  64
#define KV_D    512
#define M_ROWS  4096
#define ATT_SCALE 0.125f
#define LOG2E_F 1.44269504088896340736f

// ---------------- RoPE table (double precision, [2048][32] cos/sin) ----------------
__global__ void rope_table_kernel(float* __restrict__ cosT, float* __restrict__ sinT) {
    int pos = blockIdx.x * 2 + (threadIdx.x >> 5);
    int j   = threadIdx.x & 31;
    double invf = pow(10000.0, -(double)(2 * j) / 64.0);
    double a = (double)pos * invf;
    cosT[pos * 32 + j] = (float)cos(a);
    sinT[pos * 32 + j] = (float)sin(a);
}

// ---------------- weight transpose + convert: W[K][N] f32 -> Wt[N][K] bf16 ----------------
__global__ void wt_conv_kernel(const float* __restrict__ W, bf16_t* __restrict__ Wt,
                               int K, int N) {
    __shared__ float tile[32][33];
    int n0 = blockIdx.x * 32, k0 = blockIdx.y * 32;
    int tx = threadIdx.x & 31, ty = threadIdx.x >> 5;   // 32 x 8
#pragma unroll
    for (int i = 0; i < 4; i++) {
        int r = ty + i * 8;
        tile[r][tx] = W[(size_t)(k0 + r) * N + n0 + tx];
    }
    __syncthreads();
#pragma unroll
    for (int i = 0; i < 4; i++) {
        int r = ty + i * 8;
        Wt[(size_t)(n0 + r) * K + k0 + tx] = __float2bfloat16(tile[tx][r]);
    }
}

// ---------------- f32 -> bf16 elementwise (x4 vectorized) ----------------
struct __align__(8) bf16x4s { bf16_t x, y, z, w; };
__global__ void conv_bf16_kernel(const float* __restrict__ X, bf16_t* __restrict__ Y) {
    int i = blockIdx.x * 256 + threadIdx.x;
    float4 v = ((const float4*)X)[i];
    bf16x4s o;
    o.x = __float2bfloat16(v.x);
    o.y = __float2bfloat16(v.y);
    o.z = __float2bfloat16(v.z);
    o.w = __float2bfloat16(v.w);
    ((bf16x4s*)Y)[i] = o;
}

// ---------------- async 16B global->LDS ----------------
__device__ __forceinline__ void async_copy16(const bf16_t* g, bf16_t* l) {
    __builtin_amdgcn_global_load_lds((const __attribute__((address_space(1))) void*)g,
                                     (__attribute__((address_space(3))) void*)l, 16, 0, 0);
}

// ---------------- GEMM: C[M][N] = A[M][K] (bf16) * Bt[N][K]^T (bf16) + bias ----------------
// BN: 128 (2x2 wave grid) or 64 (4x1 wave grid, 32 rows x 64 cols per wave).
template <int BN, int ROPE, int OUTF32>
__global__ __launch_bounds__(256, 2)
void gqa_gemm_kernel(const bf16_t* __restrict__ A, const bf16_t* __restrict__ Bt,
                     const float* __restrict__ bias, void* __restrict__ Cout,
                     int M, int N, int K,
                     const float* __restrict__ cosT, const float* __restrict__ sinT) {
    __shared__ __align__(16) bf16_t As[128 * 32];
    __shared__ __align__(16) bf16_t Bs[BN * 32];
    constexpr int MI = (BN == 128) ? 4 : 2;           // 16-row frags per wave

    const int t = threadIdx.x;
    const int am0 = blockIdx.y * 128;
    const int bn0 = blockIdx.x * BN;

    const int l = t & 63, w = t >> 6;
    const int wr = (BN == 128) ? (w >> 1) : w;
    const int wc = (BN == 128) ? (w & 1) : 0;
    const int lr = l & 15, lk = l >> 4;

    f32x4 acc[MI][4];
#pragma unroll
    for (int i = 0; i < MI; i++)
#pragma unroll
        for (int j = 0; j < 4; j++) acc[i][j] = (f32x4)0.0f;

    const int srow = t >> 2;            // 0..63
    const int scol = (t & 3) * 8;
    const bf16_t* aptr = A + (size_t)(am0 + srow) * K + scol;
    const bf16_t* bptr = Bt + (size_t)(bn0 + srow) * K + scol;
    bf16_t* aLds = As + t * 8;
    bf16_t* bLds = Bs + t * 8;

    for (int k0 = 0; k0 < K; k0 += 32) {
        async_copy16(aptr + k0,                  aLds);
        async_copy16(aptr + (size_t)64 * K + k0, aLds + 2048);
#pragma unroll
        for (int rb = 0; rb < BN / 64; ++rb)
            async_copy16(bptr + (size_t)(rb * 64) * K + k0, bLds + rb * 2048);
        __syncthreads();

        bf16x8 af[MI], bfr[4];
#pragma unroll
        for (int mi = 0; mi < MI; mi++)
            af[mi] = *(const bf16x8*)&As[(wr * (MI * 16) + mi * 16 + lr) * 32 + lk * 8];
#pragma unroll
        for (int ni = 0; ni < 4; ni++)
            bfr[ni] = *(const bf16x8*)&Bs[(wc * 64 + ni * 16 + lr) * 32 + lk * 8];
#pragma unroll
        for (int mi = 0; mi < MI; mi++)
#pragma unroll
            for (int ni = 0; ni < 4; ni++)
                acc[mi][ni] = __builtin_amdgcn_mfma_f32_16x16x32_bf16(af[mi], bfr[ni],
                                                                      acc[mi][ni], 0, 0, 0);
        __syncthreads();
    }

    // Epilogue. C/D layout: col = lane&15, row = (lane>>4)*4 + reg
#pragma unroll
    for (int mi = 0; mi < MI; mi++) {
#pragma unroll
        for (int reg = 0; reg < 4; reg++) {
            int row = am0 + wr * (MI * 16) + mi * 16 + lk * 4 + reg;
            if (OUTF32) {
                float* out = (float*)Cout;
#pragma unroll
                for (int ni = 0; ni < 4; ni++) {
                    int col = bn0 + wc * 64 + ni * 16 + lr;
                    out[(size_t)row * N + col] = acc[mi][ni][reg] + bias[col];
                }
            } else if (ROPE) {
                bf16_t* out = (bf16_t*)Cout;
                int pos = row & (S_LEN - 1);
#pragma unroll
                for (int np = 0; np < 2; np++) {
                    int j = np * 16 + lr;              // d % 32 (head-local)
                    float cs = cosT[pos * 32 + j];
                    float sn = sinT[pos * 32 + j];
                    int col1 = bn0 + wc * 64 + np * 16 + lr;
                    float x1 = acc[mi][np][reg] + bias[col1];
                    float x2 = acc[mi][np + 2][reg] + bias[col1 + 32];
                    out[(size_t)row * N + col1]      = __float2bfloat16(x1 * cs - x2 * sn);
                    out[(size_t)row * N + col1 + 32] = __float2bfloat16(x2 * cs + x1 * sn);
                }
            } else {
                bf16_t* out = (bf16_t*)Cout;
#pragma unroll
                for (int ni = 0; ni < 4; ni++) {
                    int col = bn0 + wc * 64 + ni * 16 + lr;
                    out[(size_t)row * N + col] =
                        __float2bfloat16(acc[mi][ni][reg] + bias[col]);
                }
            }
        }
    }
}

// ---------------- K staging: async 16B with pre-swizzled global source ----------------
// LDS layout linear [64 key][64 d]; element (key, e) holds global d = e ^ ((key&7)<<3).
__device__ __forceinline__ void stage_K(const bf16_t* KB, bf16_t* dst, int kt, int t) {
    const int skey = t >> 3;                // 0..31
    const int c    = (t & 7) ^ (skey & 7);  // source chunk
#pragma unroll
    for (int s = 0; s < 2; ++s)
        async_copy16(KB + (size_t)(kt * 64 + s * 32 + skey) * KV_D + c * 8,
                     dst + s * 2048 + t * 8);
}

// ---------------- causal GQA flash attention ----------------
// grid (S/128, QH, B); block 256 = 4 waves; wave owns 32 q-rows (2 16-row frags).
// KV tiles of 64 keys, double-buffered, one barrier per tile.
__global__ __launch_bounds__(256, 2)
void gqa_attn_kernel(const bf16_t* __restrict__ Q, const bf16_t* __restrict__ Kb,
                     const bf16_t* __restrict__ Vb, bf16_t* __restrict__ Ctx) {
    __shared__ __align__(16) bf16_t Ks[2][64 * 64];    // linear, source-swizzled
    __shared__ __align__(16) bf16_t Vt[2][64 * 72];    // [d][key^C(d)], padded rows
    __shared__ __align__(16) bf16_t Pw[4][16 * 72];    // per-wave P, swizzled

    const int t = threadIdx.x, l = t & 63, w = t >> 6;
    const int lr = l & 15, lk = l >> 4;
    const int qt = (int)gridDim.x - 1 - (int)blockIdx.x;   // heavy blocks first
    const int h  = blockIdx.y;
    const int b  = blockIdx.z;
    const int kvh = h >> 2;
    const int q0w = qt * 128 + w * 32;

    // Q fragments: [qfrag][kslab]
    bf16x8 qf[2][2];
#pragma unroll
    for (int qfi = 0; qfi < 2; qfi++) {
        const bf16_t* qrow = Q + ((size_t)(b * S_LEN + q0w + qfi * 16 + lr)) * D_MODEL + h * HEAD_D;
        qf[qfi][0] = *(const bf16x8*)(qrow + lk * 8);
        qf[qfi][1] = *(const bf16x8*)(qrow + 32 + lk * 8);
    }

    float mrow[2][4], lrow[2][4];
    f32x4 oacc[2][4];
#pragma unroll
    for (int qfi = 0; qfi < 2; qfi++)
#pragma unroll
        for (int r = 0; r < 4; r++) {
            mrow[qfi][r] = -1e30f; lrow[qfi][r] = 0.f;
            oacc[qfi][r] = (f32x4)0.0f;   // r reused as df index for init
        }

    const int nkt = 2 * qt + 2;
    const bf16_t* KB = Kb + (size_t)b * S_LEN * KV_D + kvh * HEAD_D;
    const bf16_t* VB = Vb + (size_t)b * S_LEN * KV_D + kvh * HEAD_D;

    const int vkey = t >> 2, vd0 = (t & 3) * 16;
    bf16x8 vr0, vr1;

    // ---- prologue: stage tile 0 ----
    stage_K(KB, Ks[0], 0, t);
    {
        const bf16_t* vrow = VB + (size_t)vkey * KV_D + vd0;
        vr0 = *(const bf16x8*)vrow;
        vr1 = *(const bf16x8*)(vrow + 8);
#pragma unroll
        for (int j = 0; j < 8; j++) {
            int d = vd0 + j;
            Vt[0][d * 72 + (vkey ^ (((d >> 4) & 3) << 4))] = ((const bf16_t*)&vr0)[j];
        }
#pragma unroll
        for (int j = 0; j < 8; j++) {
            int d = vd0 + 8 + j;
            Vt[0][d * 72 + (vkey ^ (((d >> 4) & 3) << 4))] = ((const bf16_t*)&vr1)[j];
        }
    }
    __syncthreads();

    int cur = 0;
    for (int kt = 0; kt < nkt; ++kt) {
        const bool pre = (kt + 1 < nkt);
        if (pre) {
            stage_K(KB, Ks[cur ^ 1], kt + 1, t);
            const bf16_t* vrow = VB + (size_t)((kt + 1) * 64 + vkey) * KV_D + vd0;
            vr0 = *(const bf16x8*)vrow;
            vr1 = *(const bf16x8*)(vrow + 8);
        }

        if (kt * 64 <= q0w + 31) {          // wave-uniform causal skip
            const bool diag = (kt * 64 + 63 > q0w);
#pragma unroll
            for (int qfi = 0; qfi < 2; ++qfi) {
                f32x4 sfr[4];
#pragma unroll
                for (int ni = 0; ni < 4; ni++) sfr[ni] = (f32x4)0.0f;
#pragma unroll
                for (int ni = 0; ni < 4; ni++)
#pragma unroll
                    for (int ks = 0; ks < 2; ks++) {
                        bf16x8 kf = *(const bf16x8*)&Ks[cur][(ni * 16 + lr) * 64 +
                                        ((ks * 32 + lk * 8) ^ ((lr & 7) << 3))];
                        sfr[ni] = __builtin_amdgcn_mfma_f32_16x16x32_bf16(qf[qfi][ks], kf,
                                                                          sfr[ni], 0, 0, 0);
                    }

                float p[4][4], mt[4];
#pragma unroll
                for (int r = 0; r < 4; r++) mt[r] = -1e30f;
#pragma unroll
                for (int ni = 0; ni < 4; ni++)
#pragma unroll
                    for (int r = 0; r < 4; r++) {
                        float sc = sfr[ni][r] * (ATT_SCALE * LOG2E_F);
                        if (diag) {
                            int keyg = kt * 64 + ni * 16 + lr;
                            int qg   = q0w + qfi * 16 + lk * 4 + r;
                            if (keyg > qg) sc = -1e30f;
                        }
                        p[ni][r] = sc;
                        mt[r] = fmaxf(mt[r], sc);
                    }
#pragma unroll
                for (int r = 0; r < 4; r++)
                    for (int msk = 1; msk < 16; msk <<= 1)
                        mt[r] = fmaxf(mt[r], __shfl_xor(mt[r], msk));

                float csc[4], rs[4];
#pragma unroll
                for (int r = 0; r < 4; r++) {
                    float mn = fmaxf(mrow[qfi][r], mt[r]);
                    csc[r] = exp2f(mrow[qfi][r] - mn);
                    mrow[qfi][r] = mn;
                    rs[r] = 0.f;
                }
#pragma unroll
                for (int ni = 0; ni < 4; ni++)
#pragma unroll
                    for (int r = 0; r < 4; r++) {
                        float pv = exp2f(p[ni][r] - mrow[qfi][r]);
                        p[ni][r] = pv;
                        rs[r] += pv;
                    }
#pragma unroll
                for (int r = 0; r < 4; r++) {
                    for (int msk = 1; msk < 16; msk <<= 1) rs[r] += __shfl_xor(rs[r], msk);
                    lrow[qfi][r] = lrow[qfi][r] * csc[r] + rs[r];
#pragma unroll
                    for (int df = 0; df < 4; df++) oacc[qfi][df][r] *= csc[r];
                }

                // P -> per-wave LDS (swizzled: col ^ ((row>>2)&3)<<4; row = lk*4+r)
#pragma unroll
                for (int ni = 0; ni < 4; ni++)
#pragma unroll
                    for (int r = 0; r < 4; r++)
                        Pw[w][(lk * 4 + r) * 72 + ((ni * 16 + lr) ^ (lk << 4))] =
                            __float2bfloat16(p[ni][r]);

#pragma unroll
                for (int ks = 0; ks < 2; ks++) {
                    bf16x8 pf = *(const bf16x8*)&Pw[w][lr * 72 +
                                    ((ks * 32 + lk * 8) ^ (((lr >> 2) & 3) << 4))];
#pragma unroll
                    for (int df = 0; df < 4; df++) {
                        bf16x8 vf = *(const bf16x8*)&Vt[cur][(df * 16 + lr) * 72 +
                                        ((ks * 32 + lk * 8) ^ ((df & 3) << 4))];
                        oacc[qfi][df] = __builtin_amdgcn_mfma_f32_16x16x32_bf16(pf, vf,
                                            oacc[qfi][df], 0, 0, 0);
                    }
                }
            }
        }

        if (pre) {
#pragma unroll
            for (int j = 0; j < 8; j++) {
                int d = vd0 + j;
                Vt[cur ^ 1][d * 72 + (vkey ^ (((d >> 4) & 3) << 4))] = ((const bf16_t*)&vr0)[j];
            }
#pragma unroll
            for (int j = 0; j < 8; j++) {
                int d = vd0 + 8 + j;
                Vt[cur ^ 1][d * 72 + (vkey ^ (((d >> 4) & 3) << 4))] = ((const bf16_t*)&vr1)[j];
            }
        }
        __syncthreads();
        cur ^= 1;
    }

    // ---- normalize + write ctx ----
#pragma unroll
    for (int qfi = 0; qfi < 2; qfi++)
#pragma unroll
        for (int r = 0; r < 4; r++) {
            float inv = 1.0f / lrow[qfi][r];
            int qg = q0w + qfi * 16 + lk * 4 + r;
            bf16_t* crow = Ctx + ((size_t)(b * S_LEN + qg)) * D_MODEL + h * HEAD_D;
#pragma unroll
            for (int df = 0; df < 4; df++)
                crow[df * 16 + lr] = __float2bfloat16(oacc[qfi][df][r] * inv);
        }
}

extern "C" void kernel_launch(void* const* d_in, const int* in_sizes, int n_in,
                              void* d_out, int out_size, void* d_ws, size_t ws_size,
                              hipStream_t stream) {
    const float* query = (const float*)d_in[0];
    const float* key_  = (const float*)d_in[1];
    const float* value = (const float*)d_in[2];
    const float* w_q = (const float*)d_in[3];
    const float* b_q = (const float*)d_in[4];
    const float* w_k = (const float*)d_in[5];
    const float* b_k = (const float*)d_in[6];
    const float* w_v = (const float*)d_in[7];
    const float* b_v = (const float*)d_in[8];
    const float* w_o = (const float*)d_in[9];
    const float* b_o = (const float*)d_in[10];
    float* out = (float*)d_out;

    char* ws = (char*)d_ws;
    bf16_t* Abuf = (bf16_t*)(ws);                       // 16MB (A staging, reused as ctx)
    bf16_t* qb   = (bf16_t*)(ws + (size_t)(16 << 20));  // 16MB
    bf16_t* kb   = (bf16_t*)(ws + (size_t)(32 << 20));  // 4MB
    bf16_t* vb   = (bf16_t*)(ws + (size_t)(36 << 20));  // 4MB
    bf16_t* wtq  = (bf16_t*)(ws + (size_t)(40 << 20));  // 8MB
    bf16_t* wtk  = (bf16_t*)(ws + (size_t)(48 << 20));  // 2MB
    bf16_t* wtv  = (bf16_t*)(ws + (size_t)(50 << 20));  // 2MB
    bf16_t* wto  = (bf16_t*)(ws + (size_t)(52 << 20));  // 8MB
    float* cosT  = (float*)(ws + (size_t)(60 << 20));   // 256KB
    float* sinT  = (float*)(ws + (size_t)(60 << 20) + (256 << 10));

    rope_table_kernel<<<S_LEN / 2, 64, 0, stream>>>(cosT, sinT);

    wt_conv_kernel<<<dim3(D_MODEL / 32, D_MODEL / 32), 256, 0, stream>>>(w_q, wtq, D_MODEL, D_MODEL);
    wt_conv_kernel<<<dim3(KV_D / 32, D_MODEL / 32), 256, 0, stream>>>(w_k, wtk, D_MODEL, KV_D);
    wt_conv_kernel<<<dim3(KV_D / 32, D_MODEL / 32), 256, 0, stream>>>(w_v, wtv, D_MODEL, KV_D);
    wt_conv_kernel<<<dim3(D_MODEL / 32, D_MODEL / 32), 256, 0, stream>>>(w_o, wto, D_MODEL, D_MODEL);

    const int n4blocks = (M_ROWS * D_MODEL / 4) / 256;

    // Q projection (+RoPE): 512 blocks
    conv_bf16_kernel<<<n4blocks, 256, 0, stream>>>(query, Abuf);
    gqa_gemm_kernel<128, 1, 0><<<dim3(D_MODEL / 128, M_ROWS / 128), 256, 0, stream>>>(
        Abuf, wtq, b_q, qb, M_ROWS, D_MODEL, D_MODEL, cosT, sinT);
    // K projection (+RoPE): BN=64 -> 256 blocks
    conv_bf16_kernel<<<n4blocks, 256, 0, stream>>>(key_, Abuf);
    gqa_gemm_kernel<64, 1, 0><<<dim3(KV_D / 64, M_ROWS / 128), 256, 0, stream>>>(
        Abuf, wtk, b_k, kb, M_ROWS, KV_D, D_MODEL, cosT, sinT);
    // V projection: BN=64 -> 256 blocks
    conv_bf16_kernel<<<n4blocks, 256, 0, stream>>>(value, Abuf);
    gqa_gemm_kernel<64, 0, 0><<<dim3(KV_D / 64, M_ROWS / 128), 256, 0, stream>>>(
        Abuf, wtv, b_v, vb, M_ROWS, KV_D, D_MODEL, cosT, sinT);

    // Attention -> ctx (reuses Abuf)
    gqa_attn_kernel<<<dim3(S_LEN / 128, N_QH, 2), 256, 0, stream>>>(qb, kb, vb, Abuf);

    // Output projection -> fp32 d_out
    gqa_gemm_kernel<128, 0, 1><<<dim3(D_MODEL / 128, M_ROWS / 128), 256, 0, stream>>>(
        Abuf, wto, b_o, out, M_ROWS, D_MODEL, D_MODEL, cosT, sinT);
}

// Round 3
// 438.936 us; speedup vs baseline: 1.1374x; 1.0921x over previous
//
#include <hip/hip_runtime.h>
#include <hip/hip_bf16.h>

typedef __hip_bfloat16 bf16_t;
typedef __attribute__((ext_vector_type(8))) short bf16x8;
typedef __attribute__((ext_vector_type(4))) float f32x4;

#define S_LEN   2048
#define D_MODEL 2048
#define N_QH    32
#define N_KVH   8
#define HEAD_D  64
#define KV_D    512
#define M_ROWS  4096
#define ATT_SCALE 0.125f
#define LOG2E_F 1.44269504088896340736f

// ---------------- RoPE table (double precision, [2048][32] cos/sin) ----------------
__global__ void rope_table_kernel(float* __restrict__ cosT, float* __restrict__ sinT) {
    int pos = blockIdx.x * 2 + (threadIdx.x >> 5);
    int j   = threadIdx.x & 31;
    double invf = pow(10000.0, -(double)(2 * j) / 64.0);
    double a = (double)pos * invf;
    cosT[pos * 32 + j] = (float)cos(a);
    sinT[pos * 32 + j] = (float)sin(a);
}

// ---------------- weight transpose + convert: W[K][N] f32 -> Wt[N][K] bf16 ----------------
__global__ void wt_conv_kernel(const float* __restrict__ W, bf16_t* __restrict__ Wt,
                               int K, int N) {
    __shared__ float tile[32][33];
    int n0 = blockIdx.x * 32, k0 = blockIdx.y * 32;
    int tx = threadIdx.x & 31, ty = threadIdx.x >> 5;   // 32 x 8
#pragma unroll
    for (int i = 0; i < 4; i++) {
        int r = ty + i * 8;
        tile[r][tx] = W[(size_t)(k0 + r) * N + n0 + tx];
    }
    __syncthreads();
#pragma unroll
    for (int i = 0; i < 4; i++) {
        int r = ty + i * 8;
        Wt[(size_t)(n0 + r) * K + k0 + tx] = __float2bfloat16(tile[tx][r]);
    }
}

// ---------------- f32 -> bf16 elementwise (x4 vectorized) ----------------
struct __align__(8) bf16x4s { bf16_t x, y, z, w; };
__global__ void conv_bf16_kernel(const float* __restrict__ X, bf16_t* __restrict__ Y) {
    int i = blockIdx.x * 256 + threadIdx.x;
    float4 v = ((const float4*)X)[i];
    bf16x4s o;
    o.x = __float2bfloat16(v.x);
    o.y = __float2bfloat16(v.y);
    o.z = __float2bfloat16(v.z);
    o.w = __float2bfloat16(v.w);
    ((bf16x4s*)Y)[i] = o;
}

// ---------------- async 16B global->LDS ----------------
__device__ __forceinline__ void async_copy16(const bf16_t* g, bf16_t* l) {
    __builtin_amdgcn_global_load_lds((const __attribute__((address_space(1))) void*)g,
                                     (__attribute__((address_space(3))) void*)l, 16, 0, 0);
}

// ---------------- GEMM: C[M][N] = A[M][K] (bf16) * Bt[N][K]^T (bf16) + bias ----------------
// BN: 128 (2x2 wave grid) or 64 (4x1 wave grid, 32 rows x 64 cols per wave).
// VTOUT=1 (requires BN=64): write output TRANSPOSED per kv-head: vt[(b*8+kvh)*64+d][s]
template <int BN, int ROPE, int OUTF32, int VTOUT>
__global__ __launch_bounds__(256, 2)
void gqa_gemm_kernel(const bf16_t* __restrict__ A, const bf16_t* __restrict__ Bt,
                     const float* __restrict__ bias, void* __restrict__ Cout,
                     int M, int N, int K,
                     const float* __restrict__ cosT, const float* __restrict__ sinT) {
    __shared__ __align__(16) bf16_t As[128 * 32];
    __shared__ __align__(16) bf16_t Bs[BN * 32];
    __shared__ float VtE[VTOUT ? 4 * 64 * 33 : 1];
    constexpr int MI = (BN == 128) ? 4 : 2;           // 16-row frags per wave

    const int t = threadIdx.x;
    const int am0 = blockIdx.y * 128;
    const int bn0 = blockIdx.x * BN;

    const int l = t & 63, w = t >> 6;
    const int wr = (BN == 128) ? (w >> 1) : w;
    const int wc = (BN == 128) ? (w & 1) : 0;
    const int lr = l & 15, lk = l >> 4;

    f32x4 acc[MI][4];
#pragma unroll
    for (int i = 0; i < MI; i++)
#pragma unroll
        for (int j = 0; j < 4; j++) acc[i][j] = (f32x4)0.0f;

    const int srow = t >> 2;            // 0..63
    const int scol = (t & 3) * 8;
    const bf16_t* aptr = A + (size_t)(am0 + srow) * K + scol;
    const bf16_t* bptr = Bt + (size_t)(bn0 + srow) * K + scol;
    bf16_t* aLds = As + t * 8;
    bf16_t* bLds = Bs + t * 8;

    for (int k0 = 0; k0 < K; k0 += 32) {
        async_copy16(aptr + k0,                  aLds);
        async_copy16(aptr + (size_t)64 * K + k0, aLds + 2048);
#pragma unroll
        for (int rb = 0; rb < BN / 64; ++rb)
            async_copy16(bptr + (size_t)(rb * 64) * K + k0, bLds + rb * 2048);
        __syncthreads();

        bf16x8 af[MI], bfr[4];
#pragma unroll
        for (int mi = 0; mi < MI; mi++)
            af[mi] = *(const bf16x8*)&As[(wr * (MI * 16) + mi * 16 + lr) * 32 + lk * 8];
#pragma unroll
        for (int ni = 0; ni < 4; ni++)
            bfr[ni] = *(const bf16x8*)&Bs[(wc * 64 + ni * 16 + lr) * 32 + lk * 8];
#pragma unroll
        for (int mi = 0; mi < MI; mi++)
#pragma unroll
            for (int ni = 0; ni < 4; ni++)
                acc[mi][ni] = __builtin_amdgcn_mfma_f32_16x16x32_bf16(af[mi], bfr[ni],
                                                                      acc[mi][ni], 0, 0, 0);
        __syncthreads();
    }

    // Epilogue. C/D layout: col = lane&15, row = (lane>>4)*4 + reg
    if (VTOUT) {
        // stage into per-wave LDS tile [d=64][s=32] (+1 pad), then transposed store
#pragma unroll
        for (int mi = 0; mi < MI; mi++)
#pragma unroll
            for (int reg = 0; reg < 4; reg++)
#pragma unroll
                for (int ni = 0; ni < 4; ni++)
                    VtE[(w * 64 + ni * 16 + lr) * 33 + mi * 16 + lk * 4 + reg] =
                        acc[mi][ni][reg] + bias[bn0 + ni * 16 + lr];
        __syncthreads();
        const int d = l;
        const int bI = am0 >> 11;
        const int kvhI = bn0 >> 6;
        const int sl = (am0 & (S_LEN - 1)) + w * 32;
        bf16_t* dst = (bf16_t*)Cout + ((size_t)(bI * N_KVH + kvhI) * HEAD_D + d) * S_LEN + sl;
        const float* src = &VtE[(w * 64 + d) * 33];
#pragma unroll
        for (int c = 0; c < 4; c++) {
            union { bf16x8 v; bf16_t e[8]; } u;
#pragma unroll
            for (int j = 0; j < 8; j++) u.e[j] = __float2bfloat16(src[c * 8 + j]);
            *(bf16x8*)(dst + c * 8) = u.v;
        }
        return;
    }
#pragma unroll
    for (int mi = 0; mi < MI; mi++) {
#pragma unroll
        for (int reg = 0; reg < 4; reg++) {
            int row = am0 + wr * (MI * 16) + mi * 16 + lk * 4 + reg;
            if (OUTF32) {
                float* out = (float*)Cout;
#pragma unroll
                for (int ni = 0; ni < 4; ni++) {
                    int col = bn0 + wc * 64 + ni * 16 + lr;
                    out[(size_t)row * N + col] = acc[mi][ni][reg] + bias[col];
                }
            } else if (ROPE) {
                bf16_t* out = (bf16_t*)Cout;
                int pos = row & (S_LEN - 1);
#pragma unroll
                for (int np = 0; np < 2; np++) {
                    int j = np * 16 + lr;              // d % 32 (head-local)
                    float cs = cosT[pos * 32 + j];
                    float sn = sinT[pos * 32 + j];
                    int col1 = bn0 + wc * 64 + np * 16 + lr;
                    float x1 = acc[mi][np][reg] + bias[col1];
                    float x2 = acc[mi][np + 2][reg] + bias[col1 + 32];
                    out[(size_t)row * N + col1]      = __float2bfloat16(x1 * cs - x2 * sn);
                    out[(size_t)row * N + col1 + 32] = __float2bfloat16(x2 * cs + x1 * sn);
                }
            } else {
                bf16_t* out = (bf16_t*)Cout;
#pragma unroll
                for (int ni = 0; ni < 4; ni++) {
                    int col = bn0 + wc * 64 + ni * 16 + lr;
                    out[(size_t)row * N + col] =
                        __float2bfloat16(acc[mi][ni][reg] + bias[col]);
                }
            }
        }
    }
}

// ---------------- K staging: async 16B with pre-swizzled global source ----------------
// LDS layout linear [64 key][64 d]; element (key, e) holds global d = e ^ ((key&7)<<3).
__device__ __forceinline__ void stage_K(const bf16_t* KB, bf16_t* dst, int kt, int t) {
    const int skey = t >> 3;                // 0..31
    const int c    = (t & 7) ^ (skey & 7);  // source chunk
#pragma unroll
    for (int s = 0; s < 2; ++s)
        async_copy16(KB + (size_t)(kt * 64 + s * 32 + skey) * KV_D + c * 8,
                     dst + s * 2048 + t * 8);
}

// ---------------- causal GQA flash attention ----------------
// grid (S/128, QH, B) = 1024 blocks = 256 CU x 4 -> whole grid co-resident.
// 4 waves; wave owns 32 q-rows (2 16-row frags). K in dbuf LDS; V direct from
// pre-transposed global vt (L2-resident); P bounced through per-wave LDS.
__global__ __launch_bounds__(256, 4)
void gqa_attn_kernel(const bf16_t* __restrict__ Q, const bf16_t* __restrict__ Kb,
                     const bf16_t* __restrict__ VT, bf16_t* __restrict__ Ctx) {
    __shared__ __align__(16) bf16_t Ks[2][64 * 64];       // linear, source-swizzled
    __shared__ __align__(16) bf16_t Pw[4][2][16 * 72];    // [wave][qfrag], swizzled

    const int t = threadIdx.x, l = t & 63, w = t >> 6;
    const int lr = l & 15, lk = l >> 4;
    const int qt = (int)gridDim.x - 1 - (int)blockIdx.x;   // heavy blocks first
    const int h  = blockIdx.y;
    const int b  = blockIdx.z;
    const int kvh = h >> 2;
    const int q0w = qt * 128 + w * 32;

    // Q fragments: [qfrag][kslab]
    bf16x8 qf[2][2];
#pragma unroll
    for (int qfi = 0; qfi < 2; qfi++) {
        const bf16_t* qrow = Q + ((size_t)(b * S_LEN + q0w + qfi * 16 + lr)) * D_MODEL + h * HEAD_D;
        qf[qfi][0] = *(const bf16x8*)(qrow + lk * 8);
        qf[qfi][1] = *(const bf16x8*)(qrow + 32 + lk * 8);
    }

    float mrow[2][4], lrow[2][4];
    f32x4 oacc[2][4];
#pragma unroll
    for (int qfi = 0; qfi < 2; qfi++)
#pragma unroll
        for (int r = 0; r < 4; r++) {
            mrow[qfi][r] = -1e30f; lrow[qfi][r] = 0.f;
            oacc[qfi][r] = (f32x4)0.0f;
        }

    const int nkt = 2 * qt + 2;
    const bf16_t* KB  = Kb + (size_t)b * S_LEN * KV_D + kvh * HEAD_D;
    const bf16_t* VTb = VT + ((size_t)(b * N_KVH + kvh) * HEAD_D) * S_LEN;

    stage_K(KB, Ks[0], 0, t);
    __syncthreads();

    int cur = 0;
    for (int kt = 0; kt < nkt; ++kt) {
        const bool pre = (kt + 1 < nkt);
        if (pre) stage_K(KB, Ks[cur ^ 1], kt + 1, t);

        if (kt * 64 <= q0w + 31) {          // wave-uniform causal skip
            const bool diag = (kt * 64 + 63 > q0w);
#pragma unroll
            for (int qfi = 0; qfi < 2; ++qfi) {
                f32x4 sfr[4];
#pragma unroll
                for (int ni = 0; ni < 4; ni++) sfr[ni] = (f32x4)0.0f;
                __builtin_amdgcn_s_setprio(1);
#pragma unroll
                for (int ni = 0; ni < 4; ni++)
#pragma unroll
                    for (int ks = 0; ks < 2; ks++) {
                        bf16x8 kf = *(const bf16x8*)&Ks[cur][(ni * 16 + lr) * 64 +
                                        ((ks * 32 + lk * 8) ^ ((lr & 7) << 3))];
                        sfr[ni] = __builtin_amdgcn_mfma_f32_16x16x32_bf16(qf[qfi][ks], kf,
                                                                          sfr[ni], 0, 0, 0);
                    }
                __builtin_amdgcn_s_setprio(0);

                float p[4][4], mt[4];
#pragma unroll
                for (int r = 0; r < 4; r++) mt[r] = -1e30f;
#pragma unroll
                for (int ni = 0; ni < 4; ni++)
#pragma unroll
                    for (int r = 0; r < 4; r++) {
                        float sc = sfr[ni][r] * (ATT_SCALE * LOG2E_F);
                        if (diag) {
                            int keyg = kt * 64 + ni * 16 + lr;
                            int qg   = q0w + qfi * 16 + lk * 4 + r;
                            if (keyg > qg) sc = -1e30f;
                        }
                        p[ni][r] = sc;
                        mt[r] = fmaxf(mt[r], sc);
                    }
#pragma unroll
                for (int r = 0; r < 4; r++)
                    for (int msk = 1; msk < 16; msk <<= 1)
                        mt[r] = fmaxf(mt[r], __shfl_xor(mt[r], msk));

                float csc[4], rs[4];
#pragma unroll
                for (int r = 0; r < 4; r++) {
                    float mn = fmaxf(mrow[qfi][r], mt[r]);
                    csc[r] = exp2f(mrow[qfi][r] - mn);
                    mrow[qfi][r] = mn;
                    rs[r] = 0.f;
                }
#pragma unroll
                for (int ni = 0; ni < 4; ni++)
#pragma unroll
                    for (int r = 0; r < 4; r++) {
                        float pv = exp2f(p[ni][r] - mrow[qfi][r]);
                        p[ni][r] = pv;
                        rs[r] += pv;
                    }
#pragma unroll
                for (int r = 0; r < 4; r++) {
                    for (int msk = 1; msk < 16; msk <<= 1) rs[r] += __shfl_xor(rs[r], msk);
                    lrow[qfi][r] = lrow[qfi][r] * csc[r] + rs[r];
#pragma unroll
                    for (int df = 0; df < 4; df++) oacc[qfi][df][r] *= csc[r];
                }

                // P -> per-wave LDS (swizzled: col ^ (lk<<4))
#pragma unroll
                for (int ni = 0; ni < 4; ni++)
#pragma unroll
                    for (int r = 0; r < 4; r++)
                        Pw[w][qfi][(lk * 4 + r) * 72 + ((ni * 16 + lr) ^ (lk << 4))] =
                            __float2bfloat16(p[ni][r]);
            }

            // ---- PV for both q-frags; V direct from transposed global (L2) ----
            __builtin_amdgcn_s_setprio(1);
#pragma unroll
            for (int ks = 0; ks < 2; ks++) {
                bf16x8 pf0 = *(const bf16x8*)&Pw[w][0][lr * 72 +
                                ((ks * 32 + lk * 8) ^ (((lr >> 2) & 3) << 4))];
                bf16x8 pf1 = *(const bf16x8*)&Pw[w][1][lr * 72 +
                                ((ks * 32 + lk * 8) ^ (((lr >> 2) & 3) << 4))];
#pragma unroll
                for (int df = 0; df < 4; df++) {
                    bf16x8 vf = *(const bf16x8*)&VTb[(size_t)(df * 16 + lr) * S_LEN +
                                                     kt * 64 + ks * 32 + lk * 8];
                    oacc[0][df] = __builtin_amdgcn_mfma_f32_16x16x32_bf16(pf0, vf,
                                        oacc[0][df], 0, 0, 0);
                    oacc[1][df] = __builtin_amdgcn_mfma_f32_16x16x32_bf16(pf1, vf,
                                        oacc[1][df], 0, 0, 0);
                }
            }
            __builtin_amdgcn_s_setprio(0);
        }

        __syncthreads();
        cur ^= 1;
    }

    // ---- normalize + write ctx ----
#pragma unroll
    for (int qfi = 0; qfi < 2; qfi++)
#pragma unroll
        for (int r = 0; r < 4; r++) {
            float inv = 1.0f / lrow[qfi][r];
            int qg = q0w + qfi * 16 + lk * 4 + r;
            bf16_t* crow = Ctx + ((size_t)(b * S_LEN + qg)) * D_MODEL + h * HEAD_D;
#pragma unroll
            for (int df = 0; df < 4; df++)
                crow[df * 16 + lr] = __float2bfloat16(oacc[qfi][df][r] * inv);
        }
}

extern "C" void kernel_launch(void* const* d_in, const int* in_sizes, int n_in,
                              void* d_out, int out_size, void* d_ws, size_t ws_size,
                              hipStream_t stream) {
    const float* query = (const float*)d_in[0];
    const float* key_  = (const float*)d_in[1];
    const float* value = (const float*)d_in[2];
    const float* w_q = (const float*)d_in[3];
    const float* b_q = (const float*)d_in[4];
    const float* w_k = (const float*)d_in[5];
    const float* b_k = (const float*)d_in[6];
    const float* w_v = (const float*)d_in[7];
    const float* b_v = (const float*)d_in[8];
    const float* w_o = (const float*)d_in[9];
    const float* b_o = (const float*)d_in[10];
    float* out = (float*)d_out;

    char* ws = (char*)d_ws;
    bf16_t* Abuf = (bf16_t*)(ws);                       // 16MB (A staging, reused as ctx)
    bf16_t* qb   = (bf16_t*)(ws + (size_t)(16 << 20));  // 16MB
    bf16_t* kb   = (bf16_t*)(ws + (size_t)(32 << 20));  // 4MB
    bf16_t* vt   = (bf16_t*)(ws + (size_t)(36 << 20));  // 4MB (transposed V)
    bf16_t* wtq  = (bf16_t*)(ws + (size_t)(40 << 20));  // 8MB
    bf16_t* wtk  = (bf16_t*)(ws + (size_t)(48 << 20));  // 2MB
    bf16_t* wtv  = (bf16_t*)(ws + (size_t)(50 << 20));  // 2MB
    bf16_t* wto  = (bf16_t*)(ws + (size_t)(52 << 20));  // 8MB
    float* cosT  = (float*)(ws + (size_t)(60 << 20));   // 256KB
    float* sinT  = (float*)(ws + (size_t)(60 << 20) + (256 << 10));

    rope_table_kernel<<<S_LEN / 2, 64, 0, stream>>>(cosT, sinT);

    wt_conv_kernel<<<dim3(D_MODEL / 32, D_MODEL / 32), 256, 0, stream>>>(w_q, wtq, D_MODEL, D_MODEL);
    wt_conv_kernel<<<dim3(KV_D / 32, D_MODEL / 32), 256, 0, stream>>>(w_k, wtk, D_MODEL, KV_D);
    wt_conv_kernel<<<dim3(KV_D / 32, D_MODEL / 32), 256, 0, stream>>>(w_v, wtv, D_MODEL, KV_D);
    wt_conv_kernel<<<dim3(D_MODEL / 32, D_MODEL / 32), 256, 0, stream>>>(w_o, wto, D_MODEL, D_MODEL);

    const int n4blocks = (M_ROWS * D_MODEL / 4) / 256;

    // Q projection (+RoPE)
    conv_bf16_kernel<<<n4blocks, 256, 0, stream>>>(query, Abuf);
    gqa_gemm_kernel<128, 1, 0, 0><<<dim3(D_MODEL / 128, M_ROWS / 128), 256, 0, stream>>>(
        Abuf, wtq, b_q, qb, M_ROWS, D_MODEL, D_MODEL, cosT, sinT);
    // K projection (+RoPE)
    conv_bf16_kernel<<<n4blocks, 256, 0, stream>>>(key_, Abuf);
    gqa_gemm_kernel<64, 1, 0, 0><<<dim3(KV_D / 64, M_ROWS / 128), 256, 0, stream>>>(
        Abuf, wtk, b_k, kb, M_ROWS, KV_D, D_MODEL, cosT, sinT);
    // V projection -> TRANSPOSED vt[(b*8+kvh)*64+d][s]
    conv_bf16_kernel<<<n4blocks, 256, 0, stream>>>(value, Abuf);
    gqa_gemm_kernel<64, 0, 0, 1><<<dim3(KV_D / 64, M_ROWS / 128), 256, 0, stream>>>(
        Abuf, wtv, b_v, vt, M_ROWS, KV_D, D_MODEL, cosT, sinT);

    // Attention -> ctx (reuses Abuf)
    gqa_attn_kernel<<<dim3(S_LEN / 128, N_QH, 2), 256, 0, stream>>>(qb, kb, vt, Abuf);

    // Output projection -> fp32 d_out
    gqa_gemm_kernel<128, 0, 1, 0><<<dim3(D_MODEL / 128, M_ROWS / 128), 256, 0, stream>>>(
        Abuf, wto, b_o, out, M_ROWS, D_MODEL, D_MODEL, cosT, sinT);
}

// Round 4
// 348.495 us; speedup vs baseline: 1.4326x; 1.2595x over previous
//
#include <hip/hip_runtime.h>
#include <hip/hip_bf16.h>

typedef __hip_bfloat16 bf16_t;
typedef __attribute__((ext_vector_type(8))) short bf16x8;
typedef __attribute__((ext_vector_type(4))) float f32x4;

#define S_LEN   2048
#define D_MODEL 2048
#define N_QH    32
#define N_KVH   8
#define HEAD_D  64
#define KV_D    512
#define M_ROWS  4096
#define ATT_SCALE 0.125f
#define LOG2E_F 1.44269504088896340736f
#define NQT     16              // q-tiles of 128 rows

// ---------------- RoPE table (double precision, [2048][32] cos/sin) ----------------
__global__ void rope_table_kernel(float* __restrict__ cosT, float* __restrict__ sinT) {
    int pos = blockIdx.x * 2 + (threadIdx.x >> 5);
    int j   = threadIdx.x & 31;
    double invf = pow(10000.0, -(double)(2 * j) / 64.0);
    double a = (double)pos * invf;
    cosT[pos * 32 + j] = (float)cos(a);
    sinT[pos * 32 + j] = (float)sin(a);
}

// ---------------- weight transpose + convert: W[K][N] f32 -> Wt[N][K] bf16 ----------------
__global__ void wt_conv_kernel(const float* __restrict__ W, bf16_t* __restrict__ Wt,
                               int K, int N) {
    __shared__ float tile[32][33];
    int n0 = blockIdx.x * 32, k0 = blockIdx.y * 32;
    int tx = threadIdx.x & 31, ty = threadIdx.x >> 5;   // 32 x 8
#pragma unroll
    for (int i = 0; i < 4; i++) {
        int r = ty + i * 8;
        tile[r][tx] = W[(size_t)(k0 + r) * N + n0 + tx];
    }
    __syncthreads();
#pragma unroll
    for (int i = 0; i < 4; i++) {
        int r = ty + i * 8;
        Wt[(size_t)(n0 + r) * K + k0 + tx] = __float2bfloat16(tile[tx][r]);
    }
}

// ---------------- f32 -> bf16 elementwise (x4 vectorized) ----------------
struct __align__(8) bf16x4s { bf16_t x, y, z, w; };
__global__ void conv_bf16_kernel(const float* __restrict__ X, bf16_t* __restrict__ Y) {
    int i = blockIdx.x * 256 + threadIdx.x;
    float4 v = ((const float4*)X)[i];
    bf16x4s o;
    o.x = __float2bfloat16(v.x);
    o.y = __float2bfloat16(v.y);
    o.z = __float2bfloat16(v.z);
    o.w = __float2bfloat16(v.w);
    ((bf16x4s*)Y)[i] = o;
}

// ---------------- async 16B global->LDS ----------------
__device__ __forceinline__ void async_copy16(const bf16_t* g, bf16_t* l) {
    __builtin_amdgcn_global_load_lds((const __attribute__((address_space(1))) void*)g,
                                     (__attribute__((address_space(3))) void*)l, 16, 0, 0);
}

// ---------------- GEMM: C[M][N] = A[M][K] (bf16) * Bt[N][K]^T (bf16) + bias ----------------
// BN: 128 (2x2 wave grid) or 64 (4x1 wave grid, 32 rows x 64 cols per wave).
// VTOUT=1 (requires BN=64): write output TRANSPOSED per kv-head: vt[(b*8+kvh)*64+d][s]
template <int BN, int ROPE, int OUTF32, int VTOUT>
__global__ __launch_bounds__(256, 2)
void gqa_gemm_kernel(const bf16_t* __restrict__ A, const bf16_t* __restrict__ Bt,
                     const float* __restrict__ bias, void* __restrict__ Cout,
                     int M, int N, int K,
                     const float* __restrict__ cosT, const float* __restrict__ sinT) {
    __shared__ __align__(16) bf16_t As[128 * 32];
    __shared__ __align__(16) bf16_t Bs[BN * 32];
    __shared__ float VtE[VTOUT ? 4 * 64 * 33 : 1];
    constexpr int MI = (BN == 128) ? 4 : 2;           // 16-row frags per wave

    const int t = threadIdx.x;
    const int am0 = blockIdx.y * 128;
    const int bn0 = blockIdx.x * BN;

    const int l = t & 63, w = t >> 6;
    const int wr = (BN == 128) ? (w >> 1) : w;
    const int wc = (BN == 128) ? (w & 1) : 0;
    const int lr = l & 15, lk = l >> 4;

    f32x4 acc[MI][4];
#pragma unroll
    for (int i = 0; i < MI; i++)
#pragma unroll
        for (int j = 0; j < 4; j++) acc[i][j] = (f32x4)0.0f;

    const int srow = t >> 2;            // 0..63
    const int scol = (t & 3) * 8;
    const bf16_t* aptr = A + (size_t)(am0 + srow) * K + scol;
    const bf16_t* bptr = Bt + (size_t)(bn0 + srow) * K + scol;
    bf16_t* aLds = As + t * 8;
    bf16_t* bLds = Bs + t * 8;

    for (int k0 = 0; k0 < K; k0 += 32) {
        async_copy16(aptr + k0,                  aLds);
        async_copy16(aptr + (size_t)64 * K + k0, aLds + 2048);
#pragma unroll
        for (int rb = 0; rb < BN / 64; ++rb)
            async_copy16(bptr + (size_t)(rb * 64) * K + k0, bLds + rb * 2048);
        __syncthreads();

        bf16x8 af[MI], bfr[4];
#pragma unroll
        for (int mi = 0; mi < MI; mi++)
            af[mi] = *(const bf16x8*)&As[(wr * (MI * 16) + mi * 16 + lr) * 32 + lk * 8];
#pragma unroll
        for (int ni = 0; ni < 4; ni++)
            bfr[ni] = *(const bf16x8*)&Bs[(wc * 64 + ni * 16 + lr) * 32 + lk * 8];
#pragma unroll
        for (int mi = 0; mi < MI; mi++)
#pragma unroll
            for (int ni = 0; ni < 4; ni++)
                acc[mi][ni] = __builtin_amdgcn_mfma_f32_16x16x32_bf16(af[mi], bfr[ni],
                                                                      acc[mi][ni], 0, 0, 0);
        __syncthreads();
    }

    // Epilogue. C/D layout: col = lane&15, row = (lane>>4)*4 + reg
    if (VTOUT) {
        // stage into per-wave LDS tile [d=64][s=32] (+1 pad), then transposed store
#pragma unroll
        for (int mi = 0; mi < MI; mi++)
#pragma unroll
            for (int reg = 0; reg < 4; reg++)
#pragma unroll
                for (int ni = 0; ni < 4; ni++)
                    VtE[(w * 64 + ni * 16 + lr) * 33 + mi * 16 + lk * 4 + reg] =
                        acc[mi][ni][reg] + bias[bn0 + ni * 16 + lr];
        __syncthreads();
        const int d = l;
        const int bI = am0 >> 11;
        const int kvhI = bn0 >> 6;
        const int sl = (am0 & (S_LEN - 1)) + w * 32;
        bf16_t* dst = (bf16_t*)Cout + ((size_t)(bI * N_KVH + kvhI) * HEAD_D + d) * S_LEN + sl;
        const float* src = &VtE[(w * 64 + d) * 33];
#pragma unroll
        for (int c = 0; c < 4; c++) {
            union { bf16x8 v; bf16_t e[8]; } u;
#pragma unroll
            for (int j = 0; j < 8; j++) u.e[j] = __float2bfloat16(src[c * 8 + j]);
            *(bf16x8*)(dst + c * 8) = u.v;
        }
        return;
    }
#pragma unroll
    for (int mi = 0; mi < MI; mi++) {
#pragma unroll
        for (int reg = 0; reg < 4; reg++) {
            int row = am0 + wr * (MI * 16) + mi * 16 + lk * 4 + reg;
            if (OUTF32) {
                float* out = (float*)Cout;
#pragma unroll
                for (int ni = 0; ni < 4; ni++) {
                    int col = bn0 + wc * 64 + ni * 16 + lr;
                    out[(size_t)row * N + col] = acc[mi][ni][reg] + bias[col];
                }
            } else if (ROPE) {
                bf16_t* out = (bf16_t*)Cout;
                int pos = row & (S_LEN - 1);
#pragma unroll
                for (int np = 0; np < 2; np++) {
                    int j = np * 16 + lr;              // d % 32 (head-local)
                    float cs = cosT[pos * 32 + j];
                    float sn = sinT[pos * 32 + j];
                    int col1 = bn0 + wc * 64 + np * 16 + lr;
                    float x1 = acc[mi][np][reg] + bias[col1];
                    float x2 = acc[mi][np + 2][reg] + bias[col1 + 32];
                    out[(size_t)row * N + col1]      = __float2bfloat16(x1 * cs - x2 * sn);
                    out[(size_t)row * N + col1 + 32] = __float2bfloat16(x2 * cs + x1 * sn);
                }
            } else {
                bf16_t* out = (bf16_t*)Cout;
#pragma unroll
                for (int ni = 0; ni < 4; ni++) {
                    int col = bn0 + wc * 64 + ni * 16 + lr;
                    out[(size_t)row * N + col] =
                        __float2bfloat16(acc[mi][ni][reg] + bias[col]);
                }
            }
        }
    }
}

// ---------------- K staging: async 16B with pre-swizzled global source ----------------
// LDS layout linear [64 key][64 d]; element (key, e) holds global d = e ^ ((key&7)<<3).
__device__ __forceinline__ void stage_K(const bf16_t* KB, bf16_t* dst, int kt, int t) {
    const int skey = t >> 3;                // 0..31
    const int c    = (t & 7) ^ (skey & 7);  // source chunk
#pragma unroll
    for (int s = 0; s < 2; ++s)
        async_copy16(KB + (size_t)(kt * 64 + s * 32 + skey) * KV_D + c * 8,
                     dst + s * 2048 + t * 8);
}

// ---------------- V staging from pre-transposed vt: LDS [64 d][64 key], swizzled ----------------
__device__ __forceinline__ void stage_V(const bf16_t* VTb, bf16_t* dst, int kt, int t) {
    const int sd = t >> 3;                  // 0..31
    const int c  = (t & 7) ^ (sd & 7);      // source chunk (d&7 == sd&7 for both halves)
#pragma unroll
    for (int s = 0; s < 2; ++s)
        async_copy16(VTb + (size_t)(s * 32 + sd) * S_LEN + kt * 64 + c * 8,
                     dst + s * 2048 + t * 8);
}

// ---------------- causal GQA flash attention (balanced pairing) ----------------
// grid (NQT/2, QH, B) = 512 uniform blocks. Each block processes q-tiles p and
// NQT-1-p sequentially -> every block does exactly NQT*2+2 K-tile iterations.
// 4 waves; wave owns 32 q-rows. K and V double-buffered in LDS (swizzled).
__global__ __launch_bounds__(256, 2)
void gqa_attn_kernel(const bf16_t* __restrict__ Q, const bf16_t* __restrict__ Kb,
                     const bf16_t* __restrict__ VT, bf16_t* __restrict__ Ctx) {
    __shared__ __align__(16) bf16_t Ks[2][64 * 64];       // linear, source-swizzled
    __shared__ __align__(16) bf16_t Vs[2][64 * 64];       // [d][key], source-swizzled
    __shared__ __align__(16) bf16_t Pw[4][2][16 * 72];    // [wave][qfrag], swizzled

    const int t = threadIdx.x, l = t & 63, w = t >> 6;
    const int lr = l & 15, lk = l >> 4;
    const int p  = blockIdx.x;
    const int h  = blockIdx.y;
    const int b  = blockIdx.z;
    const int kvh = h >> 2;

    const bf16_t* KB  = Kb + (size_t)b * S_LEN * KV_D + kvh * HEAD_D;
    const bf16_t* VTb = VT + ((size_t)(b * N_KVH + kvh) * HEAD_D) * S_LEN;

#pragma unroll
    for (int half = 0; half < 2; ++half) {
        const int qt  = half ? (NQT - 1 - p) : p;
        const int q0w = qt * 128 + w * 32;

        // Q fragments: [qfrag][kslab]
        bf16x8 qf[2][2];
#pragma unroll
        for (int qfi = 0; qfi < 2; qfi++) {
            const bf16_t* qrow = Q + ((size_t)(b * S_LEN + q0w + qfi * 16 + lr)) * D_MODEL + h * HEAD_D;
            qf[qfi][0] = *(const bf16x8*)(qrow + lk * 8);
            qf[qfi][1] = *(const bf16x8*)(qrow + 32 + lk * 8);
        }

        float mrow[2][4], lrow[2][4];
        f32x4 oacc[2][4];
#pragma unroll
        for (int qfi = 0; qfi < 2; qfi++)
#pragma unroll
            for (int r = 0; r < 4; r++) {
                mrow[qfi][r] = -1e30f; lrow[qfi][r] = 0.f;
                oacc[qfi][r] = (f32x4)0.0f;
            }

        const int nkt = 2 * qt + 2;

        stage_K(KB, Ks[0], 0, t);
        stage_V(VTb, Vs[0], 0, t);
        __syncthreads();

        int cur = 0;
        for (int kt = 0; kt < nkt; ++kt) {
            const bool pre = (kt + 1 < nkt);
            if (pre) {
                stage_K(KB, Ks[cur ^ 1], kt + 1, t);
                stage_V(VTb, Vs[cur ^ 1], kt + 1, t);
            }

            if (kt * 64 <= q0w + 31) {          // wave-uniform causal skip
                const bool diag = (kt * 64 + 63 > q0w);
#pragma unroll
                for (int qfi = 0; qfi < 2; ++qfi) {
                    f32x4 sfr[4];
#pragma unroll
                    for (int ni = 0; ni < 4; ni++) sfr[ni] = (f32x4)0.0f;
                    __builtin_amdgcn_s_setprio(1);
#pragma unroll
                    for (int ni = 0; ni < 4; ni++)
#pragma unroll
                        for (int ks = 0; ks < 2; ks++) {
                            bf16x8 kf = *(const bf16x8*)&Ks[cur][(ni * 16 + lr) * 64 +
                                            ((ks * 32 + lk * 8) ^ ((lr & 7) << 3))];
                            sfr[ni] = __builtin_amdgcn_mfma_f32_16x16x32_bf16(qf[qfi][ks], kf,
                                                                              sfr[ni], 0, 0, 0);
                        }
                    __builtin_amdgcn_s_setprio(0);

                    float p4[4][4], mt[4];
#pragma unroll
                    for (int r = 0; r < 4; r++) mt[r] = -1e30f;
#pragma unroll
                    for (int ni = 0; ni < 4; ni++)
#pragma unroll
                        for (int r = 0; r < 4; r++) {
                            float sc = sfr[ni][r] * (ATT_SCALE * LOG2E_F);
                            if (diag) {
                                int keyg = kt * 64 + ni * 16 + lr;
                                int qg   = q0w + qfi * 16 + lk * 4 + r;
                                if (keyg > qg) sc = -1e30f;
                            }
                            p4[ni][r] = sc;
                            mt[r] = fmaxf(mt[r], sc);
                        }
#pragma unroll
                    for (int r = 0; r < 4; r++)
                        for (int msk = 1; msk < 16; msk <<= 1)
                            mt[r] = fmaxf(mt[r], __shfl_xor(mt[r], msk));

                    float csc[4], rs[4];
#pragma unroll
                    for (int r = 0; r < 4; r++) {
                        float mn = fmaxf(mrow[qfi][r], mt[r]);
                        csc[r] = exp2f(mrow[qfi][r] - mn);
                        mrow[qfi][r] = mn;
                        rs[r] = 0.f;
                    }
#pragma unroll
                    for (int ni = 0; ni < 4; ni++)
#pragma unroll
                        for (int r = 0; r < 4; r++) {
                            float pv = exp2f(p4[ni][r] - mrow[qfi][r]);
                            p4[ni][r] = pv;
                            rs[r] += pv;
                        }
#pragma unroll
                    for (int r = 0; r < 4; r++) {
                        for (int msk = 1; msk < 16; msk <<= 1) rs[r] += __shfl_xor(rs[r], msk);
                        lrow[qfi][r] = lrow[qfi][r] * csc[r] + rs[r];
#pragma unroll
                        for (int df = 0; df < 4; df++) oacc[qfi][df][r] *= csc[r];
                    }

                    // P -> per-wave LDS (swizzled: col ^ (lk<<4))
#pragma unroll
                    for (int ni = 0; ni < 4; ni++)
#pragma unroll
                        for (int r = 0; r < 4; r++)
                            Pw[w][qfi][(lk * 4 + r) * 72 + ((ni * 16 + lr) ^ (lk << 4))] =
                                __float2bfloat16(p4[ni][r]);
                }

                // ---- PV for both q-frags; V from swizzled LDS ----
                __builtin_amdgcn_s_setprio(1);
#pragma unroll
                for (int ks = 0; ks < 2; ks++) {
                    bf16x8 pf0 = *(const bf16x8*)&Pw[w][0][lr * 72 +
                                    ((ks * 32 + lk * 8) ^ (((lr >> 2) & 3) << 4))];
                    bf16x8 pf1 = *(const bf16x8*)&Pw[w][1][lr * 72 +
                                    ((ks * 32 + lk * 8) ^ (((lr >> 2) & 3) << 4))];
#pragma unroll
                    for (int df = 0; df < 4; df++) {
                        bf16x8 vf = *(const bf16x8*)&Vs[cur][(df * 16 + lr) * 64 +
                                        ((ks * 32 + lk * 8) ^ ((lr & 7) << 3))];
                        oacc[0][df] = __builtin_amdgcn_mfma_f32_16x16x32_bf16(pf0, vf,
                                            oacc[0][df], 0, 0, 0);
                        oacc[1][df] = __builtin_amdgcn_mfma_f32_16x16x32_bf16(pf1, vf,
                                            oacc[1][df], 0, 0, 0);
                    }
                }
                __builtin_amdgcn_s_setprio(0);
            }

            __syncthreads();
            cur ^= 1;
        }

        // ---- normalize + write ctx ----
#pragma unroll
        for (int qfi = 0; qfi < 2; qfi++)
#pragma unroll
            for (int r = 0; r < 4; r++) {
                float inv = 1.0f / lrow[qfi][r];
                int qg = q0w + qfi * 16 + lk * 4 + r;
                bf16_t* crow = Ctx + ((size_t)(b * S_LEN + qg)) * D_MODEL + h * HEAD_D;
#pragma unroll
                for (int df = 0; df < 4; df++)
                    crow[df * 16 + lr] = __float2bfloat16(oacc[qfi][df][r] * inv);
            }
    }
}

extern "C" void kernel_launch(void* const* d_in, const int* in_sizes, int n_in,
                              void* d_out, int out_size, void* d_ws, size_t ws_size,
                              hipStream_t stream) {
    const float* query = (const float*)d_in[0];
    const float* key_  = (const float*)d_in[1];
    const float* value = (const float*)d_in[2];
    const float* w_q = (const float*)d_in[3];
    const float* b_q = (const float*)d_in[4];
    const float* w_k = (const float*)d_in[5];
    const float* b_k = (const float*)d_in[6];
    const float* w_v = (const float*)d_in[7];
    const float* b_v = (const float*)d_in[8];
    const float* w_o = (const float*)d_in[9];
    const float* b_o = (const float*)d_in[10];
    float* out = (float*)d_out;

    char* ws = (char*)d_ws;
    bf16_t* Abuf = (bf16_t*)(ws);                       // 16MB (A staging, reused as ctx)
    bf16_t* qb   = (bf16_t*)(ws + (size_t)(16 << 20));  // 16MB
    bf16_t* kb   = (bf16_t*)(ws + (size_t)(32 << 20));  // 4MB
    bf16_t* vt   = (bf16_t*)(ws + (size_t)(36 << 20));  // 4MB (transposed V)
    bf16_t* wtq  = (bf16_t*)(ws + (size_t)(40 << 20));  // 8MB
    bf16_t* wtk  = (bf16_t*)(ws + (size_t)(48 << 20));  // 2MB
    bf16_t* wtv  = (bf16_t*)(ws + (size_t)(50 << 20));  // 2MB
    bf16_t* wto  = (bf16_t*)(ws + (size_t)(52 << 20));  // 8MB
    float* cosT  = (float*)(ws + (size_t)(60 << 20));   // 256KB
    float* sinT  = (float*)(ws + (size_t)(60 << 20) + (256 << 10));

    rope_table_kernel<<<S_LEN / 2, 64, 0, stream>>>(cosT, sinT);

    wt_conv_kernel<<<dim3(D_MODEL / 32, D_MODEL / 32), 256, 0, stream>>>(w_q, wtq, D_MODEL, D_MODEL);
    wt_conv_kernel<<<dim3(KV_D / 32, D_MODEL / 32), 256, 0, stream>>>(w_k, wtk, D_MODEL, KV_D);
    wt_conv_kernel<<<dim3(KV_D / 32, D_MODEL / 32), 256, 0, stream>>>(w_v, wtv, D_MODEL, KV_D);
    wt_conv_kernel<<<dim3(D_MODEL / 32, D_MODEL / 32), 256, 0, stream>>>(w_o, wto, D_MODEL, D_MODEL);

    const int n4blocks = (M_ROWS * D_MODEL / 4) / 256;

    // Q projection (+RoPE)
    conv_bf16_kernel<<<n4blocks, 256, 0, stream>>>(query, Abuf);
    gqa_gemm_kernel<128, 1, 0, 0><<<dim3(D_MODEL / 128, M_ROWS / 128), 256, 0, stream>>>(
        Abuf, wtq, b_q, qb, M_ROWS, D_MODEL, D_MODEL, cosT, sinT);
    // K projection (+RoPE)
    conv_bf16_kernel<<<n4blocks, 256, 0, stream>>>(key_, Abuf);
    gqa_gemm_kernel<64, 1, 0, 0><<<dim3(KV_D / 64, M_ROWS / 128), 256, 0, stream>>>(
        Abuf, wtk, b_k, kb, M_ROWS, KV_D, D_MODEL, cosT, sinT);
    // V projection -> TRANSPOSED vt[(b*8+kvh)*64+d][s]
    conv_bf16_kernel<<<n4blocks, 256, 0, stream>>>(value, Abuf);
    gqa_gemm_kernel<64, 0, 0, 1><<<dim3(KV_D / 64, M_ROWS / 128), 256, 0, stream>>>(
        Abuf, wtv, b_v, vt, M_ROWS, KV_D, D_MODEL, cosT, sinT);

    // Attention -> ctx (reuses Abuf); balanced pairing grid
    gqa_attn_kernel<<<dim3(NQT / 2, N_QH, 2), 256, 0, stream>>>(qb, kb, vt, Abuf);

    // Output projection -> fp32 d_out
    gqa_gemm_kernel<128, 0, 1, 0><<<dim3(D_MODEL / 128, M_ROWS / 128), 256, 0, stream>>>(
        Abuf, wto, b_o, out, M_ROWS, D_MODEL, D_MODEL, cosT, sinT);
}

// Round 5
// 303.882 us; speedup vs baseline: 1.6429x; 1.1468x over previous
//
#include <hip/hip_runtime.h>
#include <hip/hip_bf16.h>

typedef __hip_bfloat16 bf16_t;
typedef __attribute__((ext_vector_type(8))) short bf16x8;
typedef __attribute__((ext_vector_type(4))) float f32x4;

#define S_LEN   2048
#define D_MODEL 2048
#define N_QH    32
#define N_KVH   8
#define HEAD_D  64
#define KV_D    512
#define M_ROWS  4096
#define ATT_SCALE 0.125f
#define LOG2E_F 1.44269504088896340736f
#define NQT     16              // q-tiles of 128 rows

// ---------------- RoPE table (double precision, [2048][32] cos/sin) ----------------
__global__ void rope_table_kernel(float* __restrict__ cosT, float* __restrict__ sinT) {
    int pos = blockIdx.x * 2 + (threadIdx.x >> 5);
    int j   = threadIdx.x & 31;
    double invf = pow(10000.0, -(double)(2 * j) / 64.0);
    double a = (double)pos * invf;
    cosT[pos * 32 + j] = (float)cos(a);
    sinT[pos * 32 + j] = (float)sin(a);
}

// ---------------- weight transpose + convert: W[K][N] f32 -> Wt[N][K] bf16 ----------------
__global__ void wt_conv_kernel(const float* __restrict__ W, bf16_t* __restrict__ Wt,
                               int K, int N) {
    __shared__ float tile[32][33];
    int n0 = blockIdx.x * 32, k0 = blockIdx.y * 32;
    int tx = threadIdx.x & 31, ty = threadIdx.x >> 5;   // 32 x 8
#pragma unroll
    for (int i = 0; i < 4; i++) {
        int r = ty + i * 8;
        tile[r][tx] = W[(size_t)(k0 + r) * N + n0 + tx];
    }
    __syncthreads();
#pragma unroll
    for (int i = 0; i < 4; i++) {
        int r = ty + i * 8;
        Wt[(size_t)(n0 + r) * K + k0 + tx] = __float2bfloat16(tile[tx][r]);
    }
}

// ---------------- f32 -> bf16 elementwise (x4 vectorized) ----------------
struct __align__(8) bf16x4s { bf16_t x, y, z, w; };
__global__ void conv_bf16_kernel(const float* __restrict__ X, bf16_t* __restrict__ Y) {
    int i = blockIdx.x * 256 + threadIdx.x;
    float4 v = ((const float4*)X)[i];
    bf16x4s o;
    o.x = __float2bfloat16(v.x);
    o.y = __float2bfloat16(v.y);
    o.z = __float2bfloat16(v.z);
    o.w = __float2bfloat16(v.w);
    ((bf16x4s*)Y)[i] = o;
}

// ---------------- async 16B global->LDS ----------------
__device__ __forceinline__ void async_copy16(const bf16_t* g, bf16_t* l) {
    __builtin_amdgcn_global_load_lds((const __attribute__((address_space(1))) void*)g,
                                     (__attribute__((address_space(3))) void*)l, 16, 0, 0);
}

// ---------------- GEMM: C[M][N] = A[M][K] (bf16) * Bt[N][K]^T (bf16) + bias ----------------
// BN: 128 (2x2 wave grid) or 64 (4x1 wave grid, 32 rows x 64 cols per wave).
// VTOUT=1 (requires BN=64): write output TRANSPOSED per kv-head: vt[(b*8+kvh)*64+d][s]
template <int BN, int ROPE, int OUTF32, int VTOUT>
__global__ __launch_bounds__(256, 2)
void gqa_gemm_kernel(const bf16_t* __restrict__ A, const bf16_t* __restrict__ Bt,
                     const float* __restrict__ bias, void* __restrict__ Cout,
                     int M, int N, int K,
                     const float* __restrict__ cosT, const float* __restrict__ sinT) {
    __shared__ __align__(16) bf16_t As[128 * 32];
    __shared__ __align__(16) bf16_t Bs[BN * 32];
    __shared__ float VtE[VTOUT ? 4 * 64 * 33 : 1];
    constexpr int MI = (BN == 128) ? 4 : 2;           // 16-row frags per wave

    const int t = threadIdx.x;
    const int am0 = blockIdx.y * 128;
    const int bn0 = blockIdx.x * BN;

    const int l = t & 63, w = t >> 6;
    const int wr = (BN == 128) ? (w >> 1) : w;
    const int wc = (BN == 128) ? (w & 1) : 0;
    const int lr = l & 15, lk = l >> 4;

    f32x4 acc[MI][4];
#pragma unroll
    for (int i = 0; i < MI; i++)
#pragma unroll
        for (int j = 0; j < 4; j++) acc[i][j] = (f32x4)0.0f;

    const int srow = t >> 2;            // 0..63
    const int scol = (t & 3) * 8;
    const bf16_t* aptr = A + (size_t)(am0 + srow) * K + scol;
    const bf16_t* bptr = Bt + (size_t)(bn0 + srow) * K + scol;
    bf16_t* aLds = As + t * 8;
    bf16_t* bLds = Bs + t * 8;

    for (int k0 = 0; k0 < K; k0 += 32) {
        async_copy16(aptr + k0,                  aLds);
        async_copy16(aptr + (size_t)64 * K + k0, aLds + 2048);
#pragma unroll
        for (int rb = 0; rb < BN / 64; ++rb)
            async_copy16(bptr + (size_t)(rb * 64) * K + k0, bLds + rb * 2048);
        __syncthreads();

        bf16x8 af[MI], bfr[4];
#pragma unroll
        for (int mi = 0; mi < MI; mi++)
            af[mi] = *(const bf16x8*)&As[(wr * (MI * 16) + mi * 16 + lr) * 32 + lk * 8];
#pragma unroll
        for (int ni = 0; ni < 4; ni++)
            bfr[ni] = *(const bf16x8*)&Bs[(wc * 64 + ni * 16 + lr) * 32 + lk * 8];
#pragma unroll
        for (int mi = 0; mi < MI; mi++)
#pragma unroll
            for (int ni = 0; ni < 4; ni++)
                acc[mi][ni] = __builtin_amdgcn_mfma_f32_16x16x32_bf16(af[mi], bfr[ni],
                                                                      acc[mi][ni], 0, 0, 0);
        __syncthreads();
    }

    // Epilogue. C/D layout: col = lane&15, row = (lane>>4)*4 + reg
    if (VTOUT) {
        // stage into per-wave LDS tile [d=64][s=32] (+1 pad), then transposed store
#pragma unroll
        for (int mi = 0; mi < MI; mi++)
#pragma unroll
            for (int reg = 0; reg < 4; reg++)
#pragma unroll
                for (int ni = 0; ni < 4; ni++)
                    VtE[(w * 64 + ni * 16 + lr) * 33 + mi * 16 + lk * 4 + reg] =
                        acc[mi][ni][reg] + bias[bn0 + ni * 16 + lr];
        __syncthreads();
        const int d = l;
        const int bI = am0 >> 11;
        const int kvhI = bn0 >> 6;
        const int sl = (am0 & (S_LEN - 1)) + w * 32;
        bf16_t* dst = (bf16_t*)Cout + ((size_t)(bI * N_KVH + kvhI) * HEAD_D + d) * S_LEN + sl;
        const float* src = &VtE[(w * 64 + d) * 33];
#pragma unroll
        for (int c = 0; c < 4; c++) {
            union { bf16x8 v; bf16_t e[8]; } u;
#pragma unroll
            for (int j = 0; j < 8; j++) u.e[j] = __float2bfloat16(src[c * 8 + j]);
            *(bf16x8*)(dst + c * 8) = u.v;
        }
        return;
    }
#pragma unroll
    for (int mi = 0; mi < MI; mi++) {
#pragma unroll
        for (int reg = 0; reg < 4; reg++) {
            int row = am0 + wr * (MI * 16) + mi * 16 + lk * 4 + reg;
            if (OUTF32) {
                float* out = (float*)Cout;
#pragma unroll
                for (int ni = 0; ni < 4; ni++) {
                    int col = bn0 + wc * 64 + ni * 16 + lr;
                    out[(size_t)row * N + col] = acc[mi][ni][reg] + bias[col];
                }
            } else if (ROPE) {
                bf16_t* out = (bf16_t*)Cout;
                int pos = row & (S_LEN - 1);
#pragma unroll
                for (int np = 0; np < 2; np++) {
                    int j = np * 16 + lr;              // d % 32 (head-local)
                    float cs = cosT[pos * 32 + j];
                    float sn = sinT[pos * 32 + j];
                    int col1 = bn0 + wc * 64 + np * 16 + lr;
                    float x1 = acc[mi][np][reg] + bias[col1];
                    float x2 = acc[mi][np + 2][reg] + bias[col1 + 32];
                    out[(size_t)row * N + col1]      = __float2bfloat16(x1 * cs - x2 * sn);
                    out[(size_t)row * N + col1 + 32] = __float2bfloat16(x2 * cs + x1 * sn);
                }
            } else {
                bf16_t* out = (bf16_t*)Cout;
#pragma unroll
                for (int ni = 0; ni < 4; ni++) {
                    int col = bn0 + wc * 64 + ni * 16 + lr;
                    out[(size_t)row * N + col] =
                        __float2bfloat16(acc[mi][ni][reg] + bias[col]);
                }
            }
        }
    }
}

// ---------------- staging (512 threads: one 16B async copy per thread) ----------------
// LDS linear [64 key][64 d]; element (key, e) holds global d-chunk (e/8)^(key&7).
__device__ __forceinline__ void stage_K8(const bf16_t* KB, bf16_t* dst, int kt, int t) {
    const int skey = t >> 3;                // 0..63
    const int c    = (t & 7) ^ (skey & 7);  // source chunk
    async_copy16(KB + (size_t)(kt * 64 + skey) * KV_D + c * 8, dst + t * 8);
}
// LDS linear [64 d][64 key]; element (d, e) holds global key-chunk (e/8)^(d&7).
__device__ __forceinline__ void stage_V8(const bf16_t* VTb, bf16_t* dst, int kt, int t) {
    const int sd = t >> 3;                  // 0..63
    const int c  = (t & 7) ^ (sd & 7);      // source chunk
    async_copy16(VTb + (size_t)sd * S_LEN + kt * 64 + c * 8, dst + t * 8);
}

// ---------------- causal GQA flash attention (swapped-QK^T, 8 waves) ----------------
// grid (NQT/2, QH, B) = 512 uniform blocks, 512 threads (8 waves x 16 q-rows).
// Balanced pairing: block p does q-tiles p and NQT-1-p (34 K-tiles each).
// S^T = mfma(K,Q): lane owns ONE q-row (q = q0w + lane&15) and 16 keys ->
// in-register row reduce + 2 shuffle rounds; O^T = mfma(V^T, P^T).
__global__ __launch_bounds__(512, 4)
void gqa_attn_kernel(const bf16_t* __restrict__ Q, const bf16_t* __restrict__ Kb,
                     const bf16_t* __restrict__ VT, bf16_t* __restrict__ Ctx) {
    __shared__ __align__(16) bf16_t Ks[2][64 * 64];    // [key][d], source-swizzled
    __shared__ __align__(16) bf16_t Vs[2][64 * 64];    // [d][key], source-swizzled
    __shared__ __align__(16) bf16_t Pw[8][16 * 72];    // per-wave P [q][key]

    const int t = threadIdx.x, l = t & 63, w = t >> 6;   // w = 0..7
    const int lr = l & 15, lk = l >> 4;
    const int p  = blockIdx.x;
    const int h  = blockIdx.y;
    const int b  = blockIdx.z;
    const int kvh = h >> 2;

    const bf16_t* KB  = Kb + (size_t)b * S_LEN * KV_D + kvh * HEAD_D;
    const bf16_t* VTb = VT + ((size_t)(b * N_KVH + kvh) * HEAD_D) * S_LEN;

#pragma unroll
    for (int half = 0; half < 2; ++half) {
        const int qt  = half ? (NQT - 1 - p) : p;
        const int q0w = qt * 128 + w * 16;
        const int qg  = q0w + lr;                       // this lane's q row

        // Q fragments (A-layout: row=lane&15 -> q, k=(lane>>4)*8+i -> d)
        bf16x8 qf[2];
        {
            const bf16_t* qrow = Q + ((size_t)(b * S_LEN + qg)) * D_MODEL + h * HEAD_D;
            qf[0] = *(const bf16x8*)(qrow + lk * 8);
            qf[1] = *(const bf16x8*)(qrow + 32 + lk * 8);
        }

        float mrow = -1e30f, lrow = 0.f;
        f32x4 oaccT[4];                                 // O^T: d = df*16+lk*4+r, q = lr
#pragma unroll
        for (int df = 0; df < 4; df++) oaccT[df] = (f32x4)0.0f;

        const int nkt = 2 * qt + 2;

        stage_K8(KB, Ks[0], 0, t);
        stage_V8(VTb, Vs[0], 0, t);
        __syncthreads();

        int cur = 0;
        for (int kt = 0; kt < nkt; ++kt) {
            const bool pre = (kt + 1 < nkt);
            if (pre) {
                stage_K8(KB, Ks[cur ^ 1], kt + 1, t);
                stage_V8(VTb, Vs[cur ^ 1], kt + 1, t);
            }

            if (kt * 64 <= q0w + 15) {                  // wave-uniform causal skip
                const bool diag = (kt * 64 + 63 > q0w);

                // ---- S^T = mfma(K, Q): keys in rows, q in cols ----
                f32x4 sfrT[4];
#pragma unroll
                for (int ni = 0; ni < 4; ni++) sfrT[ni] = (f32x4)0.0f;
                __builtin_amdgcn_s_setprio(1);
#pragma unroll
                for (int ni = 0; ni < 4; ni++)
#pragma unroll
                    for (int ks = 0; ks < 2; ks++) {
                        bf16x8 kf = *(const bf16x8*)&Ks[cur][(ni * 16 + lr) * 64 +
                                        ((ks * 32 + lk * 8) ^ ((lr & 7) << 3))];
                        sfrT[ni] = __builtin_amdgcn_mfma_f32_16x16x32_bf16(kf, qf[ks],
                                                                           sfrT[ni], 0, 0, 0);
                    }
                __builtin_amdgcn_s_setprio(0);

                // ---- scale + mask + in-register row max ----
                float pv[16];
                float mx = -1e30f;
#pragma unroll
                for (int ni = 0; ni < 4; ni++)
#pragma unroll
                    for (int r = 0; r < 4; r++) {
                        float sc = sfrT[ni][r] * (ATT_SCALE * LOG2E_F);
                        if (diag) {
                            int keyg = kt * 64 + ni * 16 + lk * 4 + r;
                            if (keyg > qg) sc = -1e30f;
                        }
                        pv[ni * 4 + r] = sc;
                        mx = fmaxf(mx, sc);
                    }
                mx = fmaxf(mx, __shfl_xor(mx, 16));
                mx = fmaxf(mx, __shfl_xor(mx, 32));

                float mn  = fmaxf(mrow, mx);
                float csc = exp2f(mrow - mn);
                mrow = mn;

                float rs = 0.f;
#pragma unroll
                for (int i = 0; i < 16; i++) {
                    float e = exp2f(pv[i] - mn);
                    pv[i] = e;
                    rs += e;
                }
                rs += __shfl_xor(rs, 16);
                rs += __shfl_xor(rs, 32);
                lrow = lrow * csc + rs;
#pragma unroll
                for (int df = 0; df < 4; df++) oaccT[df] *= csc;

                // ---- P^T -> per-wave LDS as P[q][key]; 4 consecutive keys -> b64 ----
#pragma unroll
                for (int ni = 0; ni < 4; ni++) {
                    bf16x4s pk;
                    pk.x = __float2bfloat16(pv[ni * 4 + 0]);
                    pk.y = __float2bfloat16(pv[ni * 4 + 1]);
                    pk.z = __float2bfloat16(pv[ni * 4 + 2]);
                    pk.w = __float2bfloat16(pv[ni * 4 + 3]);
                    *(bf16x4s*)&Pw[w][lr * 72 + ni * 16 + lk * 4] = pk;
                }

                // ---- O^T += mfma(V^T, P^T) ----
                __builtin_amdgcn_s_setprio(1);
#pragma unroll
                for (int ks = 0; ks < 2; ks++) {
                    bf16x8 pf = *(const bf16x8*)&Pw[w][lr * 72 + ks * 32 + lk * 8];
#pragma unroll
                    for (int df = 0; df < 4; df++) {
                        bf16x8 vf = *(const bf16x8*)&Vs[cur][(df * 16 + lr) * 64 +
                                        ((ks * 32 + lk * 8) ^ ((lr & 7) << 3))];
                        oaccT[df] = __builtin_amdgcn_mfma_f32_16x16x32_bf16(vf, pf,
                                            oaccT[df], 0, 0, 0);
                    }
                }
                __builtin_amdgcn_s_setprio(0);
            }

            __syncthreads();
            cur ^= 1;
        }

        // ---- normalize + write ctx (lane owns q = qg; d = df*16+lk*4+0..3) ----
        {
            float inv = 1.0f / lrow;
            bf16_t* crow = Ctx + ((size_t)(b * S_LEN + qg)) * D_MODEL + h * HEAD_D;
#pragma unroll
            for (int df = 0; df < 4; df++) {
                bf16x4s ov;
                ov.x = __float2bfloat16(oaccT[df][0] * inv);
                ov.y = __float2bfloat16(oaccT[df][1] * inv);
                ov.z = __float2bfloat16(oaccT[df][2] * inv);
                ov.w = __float2bfloat16(oaccT[df][3] * inv);
                *(bf16x4s*)(crow + df * 16 + lk * 4) = ov;
            }
        }
    }
}

extern "C" void kernel_launch(void* const* d_in, const int* in_sizes, int n_in,
                              void* d_out, int out_size, void* d_ws, size_t ws_size,
                              hipStream_t stream) {
    const float* query = (const float*)d_in[0];
    const float* key_  = (const float*)d_in[1];
    const float* value = (const float*)d_in[2];
    const float* w_q = (const float*)d_in[3];
    const float* b_q = (const float*)d_in[4];
    const float* w_k = (const float*)d_in[5];
    const float* b_k = (const float*)d_in[6];
    const float* w_v = (const float*)d_in[7];
    const float* b_v = (const float*)d_in[8];
    const float* w_o = (const float*)d_in[9];
    const float* b_o = (const float*)d_in[10];
    float* out = (float*)d_out;

    char* ws = (char*)d_ws;
    bf16_t* Abuf = (bf16_t*)(ws);                       // 16MB (A staging, reused as ctx)
    bf16_t* qb   = (bf16_t*)(ws + (size_t)(16 << 20));  // 16MB
    bf16_t* kb   = (bf16_t*)(ws + (size_t)(32 << 20));  // 4MB
    bf16_t* vt   = (bf16_t*)(ws + (size_t)(36 << 20));  // 4MB (transposed V)
    bf16_t* wtq  = (bf16_t*)(ws + (size_t)(40 << 20));  // 8MB
    bf16_t* wtk  = (bf16_t*)(ws + (size_t)(48 << 20));  // 2MB
    bf16_t* wtv  = (bf16_t*)(ws + (size_t)(50 << 20));  // 2MB
    bf16_t* wto  = (bf16_t*)(ws + (size_t)(52 << 20));  // 8MB
    float* cosT  = (float*)(ws + (size_t)(60 << 20));   // 256KB
    float* sinT  = (float*)(ws + (size_t)(60 << 20) + (256 << 10));

    rope_table_kernel<<<S_LEN / 2, 64, 0, stream>>>(cosT, sinT);

    wt_conv_kernel<<<dim3(D_MODEL / 32, D_MODEL / 32), 256, 0, stream>>>(w_q, wtq, D_MODEL, D_MODEL);
    wt_conv_kernel<<<dim3(KV_D / 32, D_MODEL / 32), 256, 0, stream>>>(w_k, wtk, D_MODEL, KV_D);
    wt_conv_kernel<<<dim3(KV_D / 32, D_MODEL / 32), 256, 0, stream>>>(w_v, wtv, D_MODEL, KV_D);
    wt_conv_kernel<<<dim3(D_MODEL / 32, D_MODEL / 32), 256, 0, stream>>>(w_o, wto, D_MODEL, D_MODEL);

    const int n4blocks = (M_ROWS * D_MODEL / 4) / 256;

    // Q projection (+RoPE)
    conv_bf16_kernel<<<n4blocks, 256, 0, stream>>>(query, Abuf);
    gqa_gemm_kernel<128, 1, 0, 0><<<dim3(D_MODEL / 128, M_ROWS / 128), 256, 0, stream>>>(
        Abuf, wtq, b_q, qb, M_ROWS, D_MODEL, D_MODEL, cosT, sinT);
    // K projection (+RoPE)
    conv_bf16_kernel<<<n4blocks, 256, 0, stream>>>(key_, Abuf);
    gqa_gemm_kernel<64, 1, 0, 0><<<dim3(KV_D / 64, M_ROWS / 128), 256, 0, stream>>>(
        Abuf, wtk, b_k, kb, M_ROWS, KV_D, D_MODEL, cosT, sinT);
    // V projection -> TRANSPOSED vt[(b*8+kvh)*64+d][s]
    conv_bf16_kernel<<<n4blocks, 256, 0, stream>>>(value, Abuf);
    gqa_gemm_kernel<64, 0, 0, 1><<<dim3(KV_D / 64, M_ROWS / 128), 256, 0, stream>>>(
        Abuf, wtv, b_v, vt, M_ROWS, KV_D, D_MODEL, cosT, sinT);

    // Attention -> ctx (reuses Abuf); balanced pairing, 8-wave blocks
    gqa_attn_kernel<<<dim3(NQT / 2, N_QH, 2), 512, 0, stream>>>(qb, kb, vt, Abuf);

    // Output projection -> fp32 d_out
    gqa_gemm_kernel<128, 0, 1, 0><<<dim3(D_MODEL / 128, M_ROWS / 128), 256, 0, stream>>>(
        Abuf, wto, b_o, out, M_ROWS, D_MODEL, D_MODEL, cosT, sinT);
}